// Round 6
// baseline (3863.277 us; speedup 1.0000x reference)
//
#include <hip/hip_runtime.h>

// BiMPM on MI355X. Round 6: transposed-operand LSTM MFMA (A=Whh in registers,
// B=h). With gate-interleaved p, each lane's 4 acc regs are i,f,g,o of one
// (batch,hidden): no z exchange at all. h carried as packed {hi,lo} bf16 pairs
// (K'=200 with duplicated W rows) -> 1 b32 LDS write per tile, 7 b128 B-frag
// reads per wave per step. 4 waves/block, ~7 tiles each, weights ~196 VGPRs.

#define Bz 16
#define Sz 128
#define Hz 100
#define Gz 400      // 4H
#define NT 25       // Gz/16 n-tiles
#define NBK 7       // ceil(25/4) n-tile blocks per t (k_proj)
#define EPSV 1e-8f

#define XIN_CH  ((long)Sz * Bz * Gz)    // 819200
#define HOUT_CH ((long)Bz * Sz * Hz)    // 204800
#define MV_CH   ((long)Bz * Sz * 120)   // 245760
#define BSS     ((long)Bz * Sz * Sz)    // 262144

typedef __attribute__((ext_vector_type(4))) float floatx4;
typedef __attribute__((ext_vector_type(8))) __bf16 bf16x8;

union FragU { bf16x8 v; unsigned u[4]; unsigned short s[8]; };

__device__ __forceinline__ float bf2f(unsigned short h) {
  unsigned u = ((unsigned)h) << 16;
  return __builtin_bit_cast(float, u);
}
__device__ __forceinline__ unsigned short f2bf(float x) {
  unsigned u = __builtin_bit_cast(unsigned, x);
  u = u + 0x7FFFu + ((u >> 16) & 1u);   // RNE
  return (unsigned short)(u >> 16);
}
__device__ __forceinline__ float sigf(float x) { return 1.0f / (1.0f + __expf(-x)); }
__device__ __forceinline__ float tanh_fast(float x) { return 1.0f - 2.0f / (__expf(2.0f * x) + 1.0f); }

#define MFMA(a, b, c) __builtin_amdgcn_mfma_f32_16x16x32_bf16((a), (b), (c), 0, 0, 0)

__device__ __forceinline__ int pv_chain(int grp) { return (grp < 2 ? 0 : 4) + (grp & 1); }

// ---------------- projection GEMM (A=W rows, B=tokens; out[t][b][p]) ----------
// p = hidden*4+gate; W/bias rows fetched at orig = gate*Hz + hidden.
struct ProjChain {
  const int* ids;
  const float* emb;
  const float* src;
  const float* W;       // G x K fp32 (original row order)
  const float* bias;    // G fp32 (original order)
  float* out;           // S x B x G fp32: [t][b][p], gate-interleaved p
  int rev;
  int K;
  int ksteps;
};
struct Proj8 { ProjChain c[8]; };

__global__ __launch_bounds__(256) void k_proj(Proj8 P) {
  int bx = blockIdx.x;
  int c = bx / (Sz * NBK);
  int rem = bx % (Sz * NBK);
  int t = rem / NBK;
  int nb = rem % NBK;
  int wave = threadIdx.x >> 6;
  int ntile = nb * 4 + wave;
  if (ntile >= NT) return;
  int lane = threadIdx.x & 63;
  int nl = lane & 15;
  int qd = lane >> 4;

  const ProjChain ch = P.c[c];
  const int K = ch.K;
  int tp = ch.rev ? (Sz - 1 - t) : t;

  // B operand: token vector for batch nl
  const float* arow = ch.ids ? (ch.emb + (long)ch.ids[nl * Sz + tp] * K)
                             : (ch.src + ((long)nl * Sz + tp) * K);
  // A operand: W row for p = ntile*16 + nl
  int pA = ntile * 16 + nl;
  int orig_row = (pA & 3) * Hz + (pA >> 2);
  const float* wrow = ch.W + (long)orig_row * K;

  floatx4 acc = {0.f, 0.f, 0.f, 0.f};
  for (int ks = 0; ks < ch.ksteps; ++ks) {
    int k0 = ks * 32 + qd * 8;
    FragU bhi, blo, whi;
#pragma unroll
    for (int j = 0; j < 8; ++j) {
      int k = k0 + j;
      float xv = (k < K) ? arow[k] : 0.f;
      float wv = (k < K) ? wrow[k] : 0.f;
      unsigned short xh = f2bf(xv);
      bhi.s[j] = xh; blo.s[j] = f2bf(xv - bf2f(xh));
      whi.s[j] = f2bf(wv);
    }
    acc = MFMA(whi.v, bhi.v, acc);
    acc = MFMA(whi.v, blo.v, acc);
  }
  // D: row = qd*4+r = p_local, col = nl = batch
#pragma unroll
  for (int r = 0; r < 4; ++r) {
    int p = ntile * 16 + qd * 4 + r;
    acc[r] += ch.bias[(p & 3) * Hz + (p >> 2)];
  }
  *(floatx4*)(ch.out + ((long)t * Bz + nl) * Gz + ntile * 16 + qd * 4) = acc;
}

// ---------------- LSTM scan: one workgroup (4 waves) per chain ----------------
struct LstmChain {
  const float* xin;     // [t][b][p] gate-interleaved
  const float* Whh;     // G x H fp32 (original row order)
  float* hout;          // B x S x H fp32
  int rev;
  int store_all;
};
struct Lstm8 { LstmChain c[8]; };

#define MAXT 7    // max tiles per wave (waves 0-2: 7, wave 3: 4)
#define NCH 7     // K' chunks of 32 (K'=224, valid 200)
#define HPR 232   // packed h row stride in bf16 (464B, start banks spread)

__global__ __launch_bounds__(256, 1) void k_lstm(Lstm8 P) {
  __shared__ __align__(16) unsigned short hpk[2][Bz * HPR];  // packed {hi,lo}
  __shared__ float hfp[2][Bz * Hz];                          // fp32 h stage

  const LstmChain ch = P.c[blockIdx.x];
  const int tid = threadIdx.x;
  const int w = tid >> 6;
  const int lane = tid & 63;
  const int nl = lane & 15;
  const int qd = lane >> 4;

  for (int i = tid; i < 2 * Bz * HPR / 2; i += 256) ((unsigned*)hpk)[i] = 0;
  __syncthreads();

  // A-operand W fragments, K'-extended (value duplicated per hi/lo k-slot)
  FragU wa[MAXT][NCH];
#pragma unroll
  for (int i = 0; i < MAXT; ++i) {
    if (w * MAXT + i < NT) {
      int pA = (w * MAXT + i) * 16 + nl;
      const float* wr = ch.Whh + (long)((pA & 3) * Hz + (pA >> 2)) * Hz;
#pragma unroll
      for (int cc = 0; cc < NCH; ++cc) {
#pragma unroll
        for (int j = 0; j < 8; ++j) {
          int k = cc * 16 + qd * 4 + (j >> 1);
          wa[i][cc].s[j] = f2bf((k < Hz) ? wr[k] : 0.f);
        }
      }
    }
  }

  // x prefetch t=0: lane reads float4 xin[0][nl][tile*16 + qd*4]
  floatx4 xc[MAXT], xn[MAXT];
  float cstate[MAXT];
#pragma unroll
  for (int i = 0; i < MAXT; ++i) {
    cstate[i] = 0.f;
    xc[i] = floatx4{0.f, 0.f, 0.f, 0.f};
    if (w * MAXT + i < NT)
      xc[i] = *(const floatx4*)(ch.xin + (long)nl * Gz + (w * MAXT + i) * 16 + qd * 4);
  }

  for (int t = 0; t < Sz; ++t) {
    // flush h(t-1) coalesced (drains during MFMA window)
    if (ch.store_all && t > 0) {
      int pb = (t - 1) & 1;
      int sprev = ch.rev ? (Sz - t) : (t - 1);
#pragma unroll
      for (int it = 0; it < 7; ++it) {
        int idx = tid + it * 256;
        if (idx < Bz * Hz)
          ch.hout[((long)(idx / Hz) * Sz + sprev) * Hz + (idx % Hz)] = hfp[pb][idx];
      }
    }
    if (t + 1 < Sz) {
      const float* xp = ch.xin + (long)(t + 1) * Bz * Gz + (long)nl * Gz;
#pragma unroll
      for (int i = 0; i < MAXT; ++i)
        if (w * MAXT + i < NT)
          xn[i] = *(const floatx4*)(xp + (w * MAXT + i) * 16 + qd * 4);
    }
    const int rp = t & 1;
    floatx4 acc[MAXT];
#pragma unroll
    for (int i = 0; i < MAXT; ++i) acc[i] = xc[i];
#pragma unroll
    for (int cc = 0; cc < NCH; ++cc) {
      FragU bh;
      bh.v = *(const bf16x8*)(&hpk[rp][nl * HPR + cc * 32 + qd * 8]);
#pragma unroll
      for (int i = 0; i < MAXT; ++i)
        if (w * MAXT + i < NT) acc[i] = MFMA(wa[i][cc].v, bh.v, acc[i]);
    }
    // pointwise: lane owns (batch=nl, hidden=(w*MAXT+i)*4+qd); regs = i,f,g,o
    const int wp = rp ^ 1;
    const bool keep = ch.store_all || (t == Sz - 1);
#pragma unroll
    for (int i = 0; i < MAXT; ++i) {
      if (w * MAXT + i < NT) {
        float cn = sigf(acc[i][1]) * cstate[i] + sigf(acc[i][0]) * tanh_fast(acc[i][2]);
        float h = sigf(acc[i][3]) * tanh_fast(cn);
        cstate[i] = cn;
        int hd = (w * MAXT + i) * 4 + qd;
        unsigned short hh = f2bf(h);
        unsigned short hl = f2bf(h - bf2f(hh));
        *(unsigned*)(&hpk[wp][nl * HPR + 2 * hd]) = (unsigned)hh | ((unsigned)hl << 16);
        if (keep) hfp[t & 1][nl * Hz + hd] = h;
      }
    }
    __syncthreads();
#pragma unroll
    for (int i = 0; i < MAXT; ++i) xc[i] = xn[i];
  }
  // final h(127)
  {
    int pb = (Sz - 1) & 1;
    int slast = ch.rev ? 0 : (Sz - 1);
#pragma unroll
    for (int it = 0; it < 7; ++it) {
      int idx = tid + it * 256;
      if (idx < Bz * Hz)
        ch.hout[((long)(idx / Hz) * Sz + slast) * Hz + (idx % Hz)] = hfp[pb][idx];
    }
  }
}

// ---------------- cosine attention, 4 groups batched --------------------------
__global__ __launch_bounds__(256) void k_att4(const float* houtA, float* att4) {
  int bx = blockIdx.x;
  int grp = bx >> 10;
  int rem = bx & 1023;
  int b = rem >> 6;
  int pt = (rem >> 3) & 7;
  int qt = rem & 7;
  int pc = pv_chain(grp);
  const float* pv = houtA + (long)pc * HOUT_CH;
  const float* hv = houtA + (long)(pc + 2) * HOUT_CH;
  float* att = att4 + (long)grp * BSS;

  __shared__ float ps[16 * Hz];
  __shared__ float hs[16 * Hz];
  int tid = threadIdx.x;
  for (int i = tid; i < 16 * Hz; i += 256) {
    int r = i / Hz, h = i % Hz;
    ps[i] = pv[((long)b * Sz + pt * 16 + r) * Hz + h];
    hs[i] = hv[((long)b * Sz + qt * 16 + r) * Hz + h];
  }
  __syncthreads();
  int p = tid >> 4, q = tid & 15;
  const float* pr = &ps[p * Hz];
  const float* hr = &hs[q * Hz];
  float pq = 0.f, pp = 0.f, qq = 0.f;
#pragma unroll 4
  for (int h = 0; h < Hz; ++h) {
    float a = pr[h], bb = hr[h];
    pq += a * bb; pp += a * a; qq += bb * bb;
  }
  float denom = fmaxf(sqrtf(pp) * sqrtf(qq), EPSV);
  att[((long)b * Sz + pt * 16 + p) * Sz + qt * 16 + q] = pq / denom;
}

// ---------------- attention features, 4 groups batched ------------------------
__global__ __launch_bounds__(128) void k_feats4(const float* att4, const float* houtA,
                                                float* feat4) {
  int bx = blockIdx.x;
  int grp = bx / (2 * Bz * Sz);
  int rem = bx % (2 * Bz * Sz);
  int mode = rem / (Bz * Sz);
  int rem2 = rem % (Bz * Sz);
  int b = rem2 / Sz;
  int r = rem2 % Sz;
  int pc = pv_chain(grp);
  const float* pv = houtA + (long)pc * HOUT_CH;
  const float* hv = houtA + (long)(pc + 2) * HOUT_CH;
  const float* att = att4 + (long)grp * BSS;
  float* fb = feat4 + (long)grp * 4 * HOUT_CH;
  float* mean_h = fb;
  float* mean_p = fb + HOUT_CH;
  float* max_h  = fb + 2 * HOUT_CH;
  float* max_p  = fb + 3 * HOUT_CH;

  __shared__ float arow[Sz];
  int tid = threadIdx.x;
  if (mode == 0) arow[tid] = att[((long)b * Sz + r) * Sz + tid];
  else           arow[tid] = att[((long)b * Sz + tid) * Sz + r];
  __syncthreads();
  float asum = 0.f;
  for (int k = 0; k < Sz; ++k) asum += arow[k];
  const float* src = (mode == 0) ? hv : pv;
  if (tid < Hz) {
    float acc = 0.f, mx = -1e30f;
    for (int k = 0; k < Sz; ++k) {
      float a = arow[k];
      float v = src[((long)b * Sz + k) * Hz + tid];
      float pr = a * v;
      acc += pr;
      mx = fmaxf(mx, pr);
    }
    float mean = acc / fmaxf(asum, EPSV);
    long o = ((long)b * Sz + r) * Hz + tid;
    if (mode == 0) { mean_h[o] = mean; max_h[o] = mx; }
    else           { mean_p[o] = mean; max_p[o] = mx; }
  }
}

// ---------------- multi-perspective match, 24 instances batched ---------------
struct MatchArgs {
  const float* houtA;
  const float* feat4;
  float* mv;
  const float* w_full[4];
  const float* w3; const float* w4; const float* w5; const float* w6;
};

__global__ __launch_bounds__(256) void k_match24(MatchArgs M) {
  int bx = blockIdx.x;
  int grp = bx / (6 * 160);
  int rem = bx % (6 * 160);
  int inst = rem / 160;
  int idx = (rem % 160) * 256 + threadIdx.x;
  int l = idx % 20;
  int s = (idx / 20) % Sz;
  int b = idx / (20 * Sz);

  int fw = !(grp & 1);
  int word = grp < 2;
  int pc = pv_chain(grp);
  const float* PV = M.houtA + (long)pc * HOUT_CH;
  const float* HV = M.houtA + (long)(pc + 2) * HOUT_CH;
  const float* fb = M.feat4 + (long)grp * 4 * HOUT_CH;
  float* mvp = M.mv + (word ? 0 : 2) * MV_CH;
  float* mvh = mvp + MV_CH;
  long bc = fw ? (long)(Sz - 1) * Hz : 0;
  int off = fw ? 0 : 60;

  const float* v1; const float* v2; int v2s; const float* w; float* outb; int oo;
  switch (inst) {
    case 0: v1 = PV; v2 = HV + bc;          v2s = 0;  w = M.w_full[grp];      outb = mvp; oo = off;      break;
    case 1: v1 = PV; v2 = fb;               v2s = Hz; w = fw ? M.w3 : M.w4;   outb = mvp; oo = off + 20; break;
    case 2: v1 = PV; v2 = fb + 2 * HOUT_CH; v2s = Hz; w = fw ? M.w5 : M.w6;   outb = mvp; oo = off + 40; break;
    case 3: v1 = HV; v2 = PV + bc;          v2s = 0;  w = M.w_full[grp];      outb = mvh; oo = off;      break;
    case 4: v1 = HV; v2 = fb + HOUT_CH;     v2s = Hz; w = fw ? M.w3 : M.w4;   outb = mvh; oo = off + 20; break;
    default: v1 = HV; v2 = fb + 3 * HOUT_CH; v2s = Hz; w = fw ? M.w5 : M.w6;  outb = mvh; oo = off + 40; break;
  }
  const float* p1 = v1 + ((long)b * Sz + s) * Hz;
  const float* p2 = v2 + (long)b * Sz * Hz + (long)s * v2s;
  const float* wr = w + l * Hz;
  float num = 0.f, n1 = 0.f, n2 = 0.f;
#pragma unroll 4
  for (int h = 0; h < Hz; ++h) {
    float ww = wr[h];
    float wsq = ww * ww;
    float a = p1[h], c = p2[h];
    num += a * c * wsq;
    n1  += a * a * wsq;
    n2  += c * c * wsq;
  }
  float denom = fmaxf(sqrtf(n1) * sqrtf(n2), EPSV);
  outb[((long)b * Sz + s) * 120 + oo + l] = num / denom;
}

// ---------------- fused head -------------------------------------------------
__global__ __launch_bounds__(1024) void k_head(const float* houtB,
                                               const float* lw, const float* lb,
                                               const float* gw, const float* gb,
                                               const float* f1w, const float* f1b,
                                               const float* f2w, const float* f2b,
                                               float* out) {
  int b = blockIdx.x;
  __shared__ float xr[800];
  __shared__ float hwv[800];
  __shared__ float f1[200];
  int tid = threadIdx.x;
  if (tid < 800) {
    int seq = tid / Gz;
    int i = tid % Gz;
    int seg = i / Hz, j = i % Hz;
    int chain = seq * 4 + seg;
    int s_sel = (seg & 1) ? 0 : (Sz - 1);
    xr[tid] = houtB[((long)chain * Bz + b) * Sz * Hz + (long)s_sel * Hz + j];
  }
  __syncthreads();
  if (tid < 800) {
    int seq = tid / Gz;
    int o = tid % Gz;
    const float* xs = xr + seq * Gz;
    const float* lwr = lw + (long)o * Gz;
    const float* gwr = gw + (long)o * Gz;
    float al = 0.f, ag = 0.f;
#pragma unroll 4
    for (int k = 0; k < Gz; ++k) {
      float x = xs[k];
      al += x * lwr[k];
      ag += x * gwr[k];
    }
    al += lb[o];
    ag += gb[o];
    float hlin = fmaxf(al, 0.f);
    float tg = sigf(ag);
    hwv[tid] = tg * hlin + (1.f - tg) * xs[o];
  }
  __syncthreads();
  if (tid < 200) {
    const float* wr = f1w + (long)tid * 800;
    float acc = f1b[tid];
#pragma unroll 4
    for (int k = 0; k < 800; ++k) acc += hwv[k] * wr[k];
    f1[tid] = tanh_fast(acc);
  }
  __syncthreads();
  if (tid < 3) {
    const float* wr = f2w + tid * 200;
    float acc = f2b[tid];
    for (int k = 0; k < 200; ++k) acc += f1[k] * wr[k];
    out[b * 3 + tid] = acc;
  }
}

// ---------------- host orchestration -----------------------------------------
extern "C" void kernel_launch(void* const* d_in, const int* in_sizes, int n_in,
                              void* d_out, int out_size, void* d_ws, size_t ws_size,
                              hipStream_t stream) {
  (void)in_sizes; (void)n_in; (void)out_size;

  const int* p_ids  = (const int*)d_in[0];
  const int* h_ids  = (const int*)d_in[1];
  const int* cp_ids = (const int*)d_in[2];
  const int* ch_ids = (const int*)d_in[3];
  const float* word_emb = (const float*)d_in[4];
  const float* char_emb = (const float*)d_in[5];
  const float* ctx_Wih_f = (const float*)d_in[6];
  const float* ctx_Whh_f = (const float*)d_in[7];
  const float* ctx_b_f   = (const float*)d_in[8];
  const float* ctx_Wih_b = (const float*)d_in[9];
  const float* ctx_Whh_b = (const float*)d_in[10];
  const float* ctx_b_b   = (const float*)d_in[11];
  const float* chr_Wih_f = (const float*)d_in[12];
  const float* chr_Whh_f = (const float*)d_in[13];
  const float* chr_b_f   = (const float*)d_in[14];
  const float* chr_Wih_b = (const float*)d_in[15];
  const float* chr_Whh_b = (const float*)d_in[16];
  const float* chr_b_b   = (const float*)d_in[17];
  const float* agg_Wih_f = (const float*)d_in[18];
  const float* agg_Whh_f = (const float*)d_in[19];
  const float* agg_b_f   = (const float*)d_in[20];
  const float* agg_Wih_b = (const float*)d_in[21];
  const float* agg_Whh_b = (const float*)d_in[22];
  const float* agg_b_b   = (const float*)d_in[23];
  const float* mp_w1 = (const float*)d_in[24];
  const float* mp_w2 = (const float*)d_in[25];
  const float* mp_w3 = (const float*)d_in[26];
  const float* mp_w4 = (const float*)d_in[27];
  const float* mp_w5 = (const float*)d_in[28];
  const float* mp_w6 = (const float*)d_in[29];
  const float* char_w1 = (const float*)d_in[30];
  const float* char_w2 = (const float*)d_in[31];
  const float* hw_lin_w  = (const float*)d_in[32];
  const float* hw_lin_b  = (const float*)d_in[33];
  const float* hw_gate_w = (const float*)d_in[34];
  const float* hw_gate_b = (const float*)d_in[35];
  const float* fc1_w = (const float*)d_in[36];
  const float* fc1_b = (const float*)d_in[37];
  const float* fc2_w = (const float*)d_in[38];
  const float* fc2_b = (const float*)d_in[39];

  float* ws = (float*)d_ws;
  float* XIN    = ws;                         // 8 * XIN_CH (reused A -> B)
  float* ATT4   = XIN;                        // alias: dead between lstmA and projB
  float* FEAT4  = XIN + 4 * BSS;
  float* HOUT_A = XIN + 8 * XIN_CH;
  float* HOUT_B = HOUT_A + 8 * HOUT_CH;
  float* MV     = HOUT_B + 8 * HOUT_CH;
  size_t needed = (size_t)((MV + 4 * MV_CH) - ws) * 4;
  if (ws_size < needed) return;

  // ---- 1. fused phase-A projections ----
  {
    Proj8 pc{};
    const int* idv[8] = {p_ids, p_ids, h_ids, h_ids, cp_ids, cp_ids, ch_ids, ch_ids};
    for (int c = 0; c < 8; ++c) {
      int word = c < 4;
      pc.c[c].ids = idv[c];
      pc.c[c].emb = word ? word_emb : char_emb;
      pc.c[c].src = nullptr;
      pc.c[c].W    = word ? ((c & 1) ? ctx_Wih_b : ctx_Wih_f) : ((c & 1) ? chr_Wih_b : chr_Wih_f);
      pc.c[c].bias = word ? ((c & 1) ? ctx_b_b : ctx_b_f)     : ((c & 1) ? chr_b_b : chr_b_f);
      pc.c[c].out = XIN + c * XIN_CH;
      pc.c[c].rev = c & 1;
      pc.c[c].K = word ? 300 : 50;
      pc.c[c].ksteps = word ? 10 : 2;
    }
    k_proj<<<8 * Sz * NBK, 256, 0, stream>>>(pc);
  }
  // ---- 2. phase-A LSTMs ----
  {
    Lstm8 la{};
    for (int c = 0; c < 8; ++c) {
      la.c[c].xin = XIN + c * XIN_CH;
      la.c[c].Whh = (c < 4) ? ((c & 1) ? ctx_Whh_b : ctx_Whh_f)
                            : ((c & 1) ? chr_Whh_b : chr_Whh_f);
      la.c[c].hout = HOUT_A + c * HOUT_CH;
      la.c[c].rev = c & 1;
      la.c[c].store_all = 1;
    }
    k_lstm<<<8, 256, 0, stream>>>(la);
  }
  // ---- 3-5. branch ----
  k_att4<<<4 * Bz * 64, 256, 0, stream>>>(HOUT_A, ATT4);
  k_feats4<<<4 * 2 * Bz * Sz, 128, 0, stream>>>(ATT4, HOUT_A, FEAT4);
  {
    MatchArgs m{};
    m.houtA = HOUT_A; m.feat4 = FEAT4; m.mv = MV;
    m.w_full[0] = mp_w1; m.w_full[1] = mp_w2; m.w_full[2] = char_w1; m.w_full[3] = char_w2;
    m.w3 = mp_w3; m.w4 = mp_w4; m.w5 = mp_w5; m.w6 = mp_w6;
    k_match24<<<4 * 6 * 160, 256, 0, stream>>>(m);
  }
  // ---- 6. phase-B projections (K=120) ----
  {
    Proj8 pa{};
    for (int c = 0; c < 8; ++c) {
      pa.c[c].ids = nullptr; pa.c[c].emb = nullptr;
      pa.c[c].src = MV + (c >> 1) * MV_CH;
      pa.c[c].W = (c & 1) ? agg_Wih_b : agg_Wih_f;
      pa.c[c].bias = (c & 1) ? agg_b_b : agg_b_f;
      pa.c[c].out = XIN + c * XIN_CH;
      pa.c[c].rev = c & 1;
      pa.c[c].K = 120;
      pa.c[c].ksteps = 4;
    }
    k_proj<<<8 * Sz * NBK, 256, 0, stream>>>(pa);
  }
  // ---- 7. phase-B LSTMs ----
  {
    Lstm8 la{};
    for (int c = 0; c < 8; ++c) {
      la.c[c].xin = XIN + c * XIN_CH;
      la.c[c].Whh = (c & 1) ? agg_Whh_b : agg_Whh_f;
      la.c[c].hout = HOUT_B + c * HOUT_CH;
      la.c[c].rev = c & 1;
      la.c[c].store_all = 0;
    }
    k_lstm<<<8, 256, 0, stream>>>(la);
  }
  // ---- 8. fused head ----
  k_head<<<Bz, 1024, 0, stream>>>(HOUT_B, hw_lin_w, hw_lin_b, hw_gate_w, hw_gate_b,
                                  fc1_w, fc1_b, fc2_w, fc2_b, (float*)d_out);
}

// Round 7
// 1202.788 us; speedup vs baseline: 3.2119x; 3.2119x over previous
//
#include <hip/hip_runtime.h>

// BiMPM on MI355X. Round 7: transposed-operand LSTM (A=Whh regs, B=h packed
// {hi,lo} bf16, K'=200) as in round 6, but 8 waves x <=4 tiles round-robin
// instead of 4 waves x 7 tiles: weight frags 112 VGPRs, total ~200 -> no
// scratch spill (round 6 hit the 256 cap and spilled -> 6x regression).

#define Bz 16
#define Sz 128
#define Hz 100
#define Gz 400      // 4H
#define NT 25       // Gz/16 n-tiles
#define NBK 7       // ceil(25/4) n-tile blocks per t (k_proj)
#define EPSV 1e-8f

#define XIN_CH  ((long)Sz * Bz * Gz)    // 819200
#define HOUT_CH ((long)Bz * Sz * Hz)    // 204800
#define MV_CH   ((long)Bz * Sz * 120)   // 245760
#define BSS     ((long)Bz * Sz * Sz)    // 262144

typedef __attribute__((ext_vector_type(4))) float floatx4;
typedef __attribute__((ext_vector_type(8))) __bf16 bf16x8;

union FragU { bf16x8 v; unsigned u[4]; unsigned short s[8]; };

__device__ __forceinline__ float bf2f(unsigned short h) {
  unsigned u = ((unsigned)h) << 16;
  return __builtin_bit_cast(float, u);
}
__device__ __forceinline__ unsigned short f2bf(float x) {
  unsigned u = __builtin_bit_cast(unsigned, x);
  u = u + 0x7FFFu + ((u >> 16) & 1u);   // RNE
  return (unsigned short)(u >> 16);
}
__device__ __forceinline__ float sigf(float x) { return 1.0f / (1.0f + __expf(-x)); }
__device__ __forceinline__ float tanh_fast(float x) { return 1.0f - 2.0f / (__expf(2.0f * x) + 1.0f); }

#define MFMA(a, b, c) __builtin_amdgcn_mfma_f32_16x16x32_bf16((a), (b), (c), 0, 0, 0)

__device__ __forceinline__ int pv_chain(int grp) { return (grp < 2 ? 0 : 4) + (grp & 1); }

// ---------------- projection GEMM (A=W rows, B=tokens; out[t][b][p]) ----------
// p = hidden*4+gate; W/bias rows fetched at orig = gate*Hz + hidden.
struct ProjChain {
  const int* ids;
  const float* emb;
  const float* src;
  const float* W;       // G x K fp32 (original row order)
  const float* bias;    // G fp32 (original order)
  float* out;           // S x B x G fp32: [t][b][p], gate-interleaved p
  int rev;
  int K;
  int ksteps;
};
struct Proj8 { ProjChain c[8]; };

__global__ __launch_bounds__(256) void k_proj(Proj8 P) {
  int bx = blockIdx.x;
  int c = bx / (Sz * NBK);
  int rem = bx % (Sz * NBK);
  int t = rem / NBK;
  int nb = rem % NBK;
  int wave = threadIdx.x >> 6;
  int ntile = nb * 4 + wave;
  if (ntile >= NT) return;
  int lane = threadIdx.x & 63;
  int nl = lane & 15;
  int qd = lane >> 4;

  const ProjChain ch = P.c[c];
  const int K = ch.K;
  int tp = ch.rev ? (Sz - 1 - t) : t;

  // B operand: token vector for batch nl
  const float* arow = ch.ids ? (ch.emb + (long)ch.ids[nl * Sz + tp] * K)
                             : (ch.src + ((long)nl * Sz + tp) * K);
  // A operand: W row for p = ntile*16 + nl
  int pA = ntile * 16 + nl;
  int orig_row = (pA & 3) * Hz + (pA >> 2);
  const float* wrow = ch.W + (long)orig_row * K;

  floatx4 acc = {0.f, 0.f, 0.f, 0.f};
  for (int ks = 0; ks < ch.ksteps; ++ks) {
    int k0 = ks * 32 + qd * 8;
    FragU bhi, blo, whi;
#pragma unroll
    for (int j = 0; j < 8; ++j) {
      int k = k0 + j;
      float xv = (k < K) ? arow[k] : 0.f;
      float wv = (k < K) ? wrow[k] : 0.f;
      unsigned short xh = f2bf(xv);
      bhi.s[j] = xh; blo.s[j] = f2bf(xv - bf2f(xh));
      whi.s[j] = f2bf(wv);
    }
    acc = MFMA(whi.v, bhi.v, acc);
    acc = MFMA(whi.v, blo.v, acc);
  }
  // D: row = qd*4+r = p_local, col = nl = batch
#pragma unroll
  for (int r = 0; r < 4; ++r) {
    int p = ntile * 16 + qd * 4 + r;
    acc[r] += ch.bias[(p & 3) * Hz + (p >> 2)];
  }
  *(floatx4*)(ch.out + ((long)t * Bz + nl) * Gz + ntile * 16 + qd * 4) = acc;
}

// ---------------- LSTM scan: one workgroup (8 waves) per chain ----------------
struct LstmChain {
  const float* xin;     // [t][b][p] gate-interleaved
  const float* Whh;     // G x H fp32 (original row order)
  float* hout;          // B x S x H fp32
  int rev;
  int store_all;
};
struct Lstm8 { LstmChain c[8]; };

#define NW 8      // waves per block
#define TPW 4     // max tiles per wave; tile = i*NW + w (wave 0: 4, others: 3)
#define NCH 7     // K' chunks of 32 (K'=224, valid 200)
#define HPR 232   // packed h row stride in bf16 (464B; 2-way banks only)

__global__ __launch_bounds__(512, 2) void k_lstm(Lstm8 P) {
  __shared__ __align__(16) unsigned short hpk[2][Bz * HPR];  // packed {hi,lo}
  __shared__ float hfp[2][Bz * Hz];                          // fp32 h stage

  const LstmChain ch = P.c[blockIdx.x];
  const int tid = threadIdx.x;
  const int w = tid >> 6;
  const int lane = tid & 63;
  const int nl = lane & 15;
  const int qd = lane >> 4;

  for (int i = tid; i < 2 * Bz * HPR / 2; i += 512) ((unsigned*)hpk)[i] = 0;
  __syncthreads();

  // A-operand W fragments, K'-extended (value duplicated per hi/lo k-slot)
  FragU wa[TPW][NCH];
#pragma unroll
  for (int i = 0; i < TPW; ++i) {
    int tile = i * NW + w;
    if (tile < NT) {
      int pA = tile * 16 + nl;
      const float* wr = ch.Whh + (long)((pA & 3) * Hz + (pA >> 2)) * Hz;
#pragma unroll
      for (int cc = 0; cc < NCH; ++cc) {
#pragma unroll
        for (int j = 0; j < 8; ++j) {
          int k = cc * 16 + qd * 4 + (j >> 1);
          wa[i][cc].s[j] = f2bf((k < Hz) ? wr[k] : 0.f);
        }
      }
    }
  }

  // x prefetch t=0: lane reads float4 xin[0][nl][tile*16 + qd*4]
  floatx4 xc[TPW], xn[TPW];
  float cstate[TPW];
#pragma unroll
  for (int i = 0; i < TPW; ++i) {
    cstate[i] = 0.f;
    xc[i] = floatx4{0.f, 0.f, 0.f, 0.f};
    if (i * NW + w < NT)
      xc[i] = *(const floatx4*)(ch.xin + (long)nl * Gz + (i * NW + w) * 16 + qd * 4);
  }

  for (int t = 0; t < Sz; ++t) {
    // flush h(t-1) coalesced (drains during MFMA window)
    if (ch.store_all && t > 0) {
      int pb = (t - 1) & 1;
      int sprev = ch.rev ? (Sz - t) : (t - 1);
#pragma unroll
      for (int it = 0; it < 4; ++it) {
        int idx = tid + it * 512;
        if (idx < Bz * Hz)
          ch.hout[((long)(idx / Hz) * Sz + sprev) * Hz + (idx % Hz)] = hfp[pb][idx];
      }
    }
    if (t + 1 < Sz) {
      const float* xp = ch.xin + (long)(t + 1) * Bz * Gz + (long)nl * Gz;
#pragma unroll
      for (int i = 0; i < TPW; ++i)
        if (i * NW + w < NT)
          xn[i] = *(const floatx4*)(xp + (i * NW + w) * 16 + qd * 4);
    }
    const int rp = t & 1;
    floatx4 acc[TPW];
#pragma unroll
    for (int i = 0; i < TPW; ++i) acc[i] = xc[i];
#pragma unroll
    for (int cc = 0; cc < NCH; ++cc) {
      FragU bh;
      bh.v = *(const bf16x8*)(&hpk[rp][nl * HPR + cc * 32 + qd * 8]);
#pragma unroll
      for (int i = 0; i < TPW; ++i)
        if (i * NW + w < NT) acc[i] = MFMA(wa[i][cc].v, bh.v, acc[i]);
    }
    // pointwise: lane owns (batch=nl, hidden=tile*4+qd); regs = i,f,g,o
    const int wp = rp ^ 1;
    const bool keep = ch.store_all || (t == Sz - 1);
#pragma unroll
    for (int i = 0; i < TPW; ++i) {
      int tile = i * NW + w;
      if (tile < NT) {
        float cn = sigf(acc[i][1]) * cstate[i] + sigf(acc[i][0]) * tanh_fast(acc[i][2]);
        float h = sigf(acc[i][3]) * tanh_fast(cn);
        cstate[i] = cn;
        int hd = tile * 4 + qd;
        unsigned short hh = f2bf(h);
        unsigned short hl = f2bf(h - bf2f(hh));
        *(unsigned*)(&hpk[wp][nl * HPR + 2 * hd]) = (unsigned)hh | ((unsigned)hl << 16);
        if (keep) hfp[t & 1][nl * Hz + hd] = h;
      }
    }
    __syncthreads();
#pragma unroll
    for (int i = 0; i < TPW; ++i) xc[i] = xn[i];
  }
  // final h(127)
  {
    int pb = (Sz - 1) & 1;
    int slast = ch.rev ? 0 : (Sz - 1);
#pragma unroll
    for (int it = 0; it < 4; ++it) {
      int idx = tid + it * 512;
      if (idx < Bz * Hz)
        ch.hout[((long)(idx / Hz) * Sz + slast) * Hz + (idx % Hz)] = hfp[pb][idx];
    }
  }
}

// ---------------- cosine attention, 4 groups batched --------------------------
__global__ __launch_bounds__(256) void k_att4(const float* houtA, float* att4) {
  int bx = blockIdx.x;
  int grp = bx >> 10;
  int rem = bx & 1023;
  int b = rem >> 6;
  int pt = (rem >> 3) & 7;
  int qt = rem & 7;
  int pc = pv_chain(grp);
  const float* pv = houtA + (long)pc * HOUT_CH;
  const float* hv = houtA + (long)(pc + 2) * HOUT_CH;
  float* att = att4 + (long)grp * BSS;

  __shared__ float ps[16 * Hz];
  __shared__ float hs[16 * Hz];
  int tid = threadIdx.x;
  for (int i = tid; i < 16 * Hz; i += 256) {
    int r = i / Hz, h = i % Hz;
    ps[i] = pv[((long)b * Sz + pt * 16 + r) * Hz + h];
    hs[i] = hv[((long)b * Sz + qt * 16 + r) * Hz + h];
  }
  __syncthreads();
  int p = tid >> 4, q = tid & 15;
  const float* pr = &ps[p * Hz];
  const float* hr = &hs[q * Hz];
  float pq = 0.f, pp = 0.f, qq = 0.f;
#pragma unroll 4
  for (int h = 0; h < Hz; ++h) {
    float a = pr[h], bb = hr[h];
    pq += a * bb; pp += a * a; qq += bb * bb;
  }
  float denom = fmaxf(sqrtf(pp) * sqrtf(qq), EPSV);
  att[((long)b * Sz + pt * 16 + p) * Sz + qt * 16 + q] = pq / denom;
}

// ---------------- attention features, 4 groups batched ------------------------
__global__ __launch_bounds__(128) void k_feats4(const float* att4, const float* houtA,
                                                float* feat4) {
  int bx = blockIdx.x;
  int grp = bx / (2 * Bz * Sz);
  int rem = bx % (2 * Bz * Sz);
  int mode = rem / (Bz * Sz);
  int rem2 = rem % (Bz * Sz);
  int b = rem2 / Sz;
  int r = rem2 % Sz;
  int pc = pv_chain(grp);
  const float* pv = houtA + (long)pc * HOUT_CH;
  const float* hv = houtA + (long)(pc + 2) * HOUT_CH;
  const float* att = att4 + (long)grp * BSS;
  float* fb = feat4 + (long)grp * 4 * HOUT_CH;
  float* mean_h = fb;
  float* mean_p = fb + HOUT_CH;
  float* max_h  = fb + 2 * HOUT_CH;
  float* max_p  = fb + 3 * HOUT_CH;

  __shared__ float arow[Sz];
  int tid = threadIdx.x;
  if (mode == 0) arow[tid] = att[((long)b * Sz + r) * Sz + tid];
  else           arow[tid] = att[((long)b * Sz + tid) * Sz + r];
  __syncthreads();
  float asum = 0.f;
  for (int k = 0; k < Sz; ++k) asum += arow[k];
  const float* src = (mode == 0) ? hv : pv;
  if (tid < Hz) {
    float acc = 0.f, mx = -1e30f;
    for (int k = 0; k < Sz; ++k) {
      float a = arow[k];
      float v = src[((long)b * Sz + k) * Hz + tid];
      float pr = a * v;
      acc += pr;
      mx = fmaxf(mx, pr);
    }
    float mean = acc / fmaxf(asum, EPSV);
    long o = ((long)b * Sz + r) * Hz + tid;
    if (mode == 0) { mean_h[o] = mean; max_h[o] = mx; }
    else           { mean_p[o] = mean; max_p[o] = mx; }
  }
}

// ---------------- multi-perspective match, 24 instances batched ---------------
struct MatchArgs {
  const float* houtA;
  const float* feat4;
  float* mv;
  const float* w_full[4];
  const float* w3; const float* w4; const float* w5; const float* w6;
};

__global__ __launch_bounds__(256) void k_match24(MatchArgs M) {
  int bx = blockIdx.x;
  int grp = bx / (6 * 160);
  int rem = bx % (6 * 160);
  int inst = rem / 160;
  int idx = (rem % 160) * 256 + threadIdx.x;
  int l = idx % 20;
  int s = (idx / 20) % Sz;
  int b = idx / (20 * Sz);

  int fw = !(grp & 1);
  int word = grp < 2;
  int pc = pv_chain(grp);
  const float* PV = M.houtA + (long)pc * HOUT_CH;
  const float* HV = M.houtA + (long)(pc + 2) * HOUT_CH;
  const float* fb = M.feat4 + (long)grp * 4 * HOUT_CH;
  float* mvp = M.mv + (word ? 0 : 2) * MV_CH;
  float* mvh = mvp + MV_CH;
  long bc = fw ? (long)(Sz - 1) * Hz : 0;
  int off = fw ? 0 : 60;

  const float* v1; const float* v2; int v2s; const float* w; float* outb; int oo;
  switch (inst) {
    case 0: v1 = PV; v2 = HV + bc;          v2s = 0;  w = M.w_full[grp];      outb = mvp; oo = off;      break;
    case 1: v1 = PV; v2 = fb;               v2s = Hz; w = fw ? M.w3 : M.w4;   outb = mvp; oo = off + 20; break;
    case 2: v1 = PV; v2 = fb + 2 * HOUT_CH; v2s = Hz; w = fw ? M.w5 : M.w6;   outb = mvp; oo = off + 40; break;
    case 3: v1 = HV; v2 = PV + bc;          v2s = 0;  w = M.w_full[grp];      outb = mvh; oo = off;      break;
    case 4: v1 = HV; v2 = fb + HOUT_CH;     v2s = Hz; w = fw ? M.w3 : M.w4;   outb = mvh; oo = off + 20; break;
    default: v1 = HV; v2 = fb + 3 * HOUT_CH; v2s = Hz; w = fw ? M.w5 : M.w6;  outb = mvh; oo = off + 40; break;
  }
  const float* p1 = v1 + ((long)b * Sz + s) * Hz;
  const float* p2 = v2 + (long)b * Sz * Hz + (long)s * v2s;
  const float* wr = w + l * Hz;
  float num = 0.f, n1 = 0.f, n2 = 0.f;
#pragma unroll 4
  for (int h = 0; h < Hz; ++h) {
    float ww = wr[h];
    float wsq = ww * ww;
    float a = p1[h], c = p2[h];
    num += a * c * wsq;
    n1  += a * a * wsq;
    n2  += c * c * wsq;
  }
  float denom = fmaxf(sqrtf(n1) * sqrtf(n2), EPSV);
  outb[((long)b * Sz + s) * 120 + oo + l] = num / denom;
}

// ---------------- fused head -------------------------------------------------
__global__ __launch_bounds__(1024) void k_head(const float* houtB,
                                               const float* lw, const float* lb,
                                               const float* gw, const float* gb,
                                               const float* f1w, const float* f1b,
                                               const float* f2w, const float* f2b,
                                               float* out) {
  int b = blockIdx.x;
  __shared__ float xr[800];
  __shared__ float hwv[800];
  __shared__ float f1[200];
  int tid = threadIdx.x;
  if (tid < 800) {
    int seq = tid / Gz;
    int i = tid % Gz;
    int seg = i / Hz, j = i % Hz;
    int chain = seq * 4 + seg;
    int s_sel = (seg & 1) ? 0 : (Sz - 1);
    xr[tid] = houtB[((long)chain * Bz + b) * Sz * Hz + (long)s_sel * Hz + j];
  }
  __syncthreads();
  if (tid < 800) {
    int seq = tid / Gz;
    int o = tid % Gz;
    const float* xs = xr + seq * Gz;
    const float* lwr = lw + (long)o * Gz;
    const float* gwr = gw + (long)o * Gz;
    float al = 0.f, ag = 0.f;
#pragma unroll 4
    for (int k = 0; k < Gz; ++k) {
      float x = xs[k];
      al += x * lwr[k];
      ag += x * gwr[k];
    }
    al += lb[o];
    ag += gb[o];
    float hlin = fmaxf(al, 0.f);
    float tg = sigf(ag);
    hwv[tid] = tg * hlin + (1.f - tg) * xs[o];
  }
  __syncthreads();
  if (tid < 200) {
    const float* wr = f1w + (long)tid * 800;
    float acc = f1b[tid];
#pragma unroll 4
    for (int k = 0; k < 800; ++k) acc += hwv[k] * wr[k];
    f1[tid] = tanh_fast(acc);
  }
  __syncthreads();
  if (tid < 3) {
    const float* wr = f2w + tid * 200;
    float acc = f2b[tid];
    for (int k = 0; k < 200; ++k) acc += f1[k] * wr[k];
    out[b * 3 + tid] = acc;
  }
}

// ---------------- host orchestration -----------------------------------------
extern "C" void kernel_launch(void* const* d_in, const int* in_sizes, int n_in,
                              void* d_out, int out_size, void* d_ws, size_t ws_size,
                              hipStream_t stream) {
  (void)in_sizes; (void)n_in; (void)out_size;

  const int* p_ids  = (const int*)d_in[0];
  const int* h_ids  = (const int*)d_in[1];
  const int* cp_ids = (const int*)d_in[2];
  const int* ch_ids = (const int*)d_in[3];
  const float* word_emb = (const float*)d_in[4];
  const float* char_emb = (const float*)d_in[5];
  const float* ctx_Wih_f = (const float*)d_in[6];
  const float* ctx_Whh_f = (const float*)d_in[7];
  const float* ctx_b_f   = (const float*)d_in[8];
  const float* ctx_Wih_b = (const float*)d_in[9];
  const float* ctx_Whh_b = (const float*)d_in[10];
  const float* ctx_b_b   = (const float*)d_in[11];
  const float* chr_Wih_f = (const float*)d_in[12];
  const float* chr_Whh_f = (const float*)d_in[13];
  const float* chr_b_f   = (const float*)d_in[14];
  const float* chr_Wih_b = (const float*)d_in[15];
  const float* chr_Whh_b = (const float*)d_in[16];
  const float* chr_b_b   = (const float*)d_in[17];
  const float* agg_Wih_f = (const float*)d_in[18];
  const float* agg_Whh_f = (const float*)d_in[19];
  const float* agg_b_f   = (const float*)d_in[20];
  const float* agg_Wih_b = (const float*)d_in[21];
  const float* agg_Whh_b = (const float*)d_in[22];
  const float* agg_b_b   = (const float*)d_in[23];
  const float* mp_w1 = (const float*)d_in[24];
  const float* mp_w2 = (const float*)d_in[25];
  const float* mp_w3 = (const float*)d_in[26];
  const float* mp_w4 = (const float*)d_in[27];
  const float* mp_w5 = (const float*)d_in[28];
  const float* mp_w6 = (const float*)d_in[29];
  const float* char_w1 = (const float*)d_in[30];
  const float* char_w2 = (const float*)d_in[31];
  const float* hw_lin_w  = (const float*)d_in[32];
  const float* hw_lin_b  = (const float*)d_in[33];
  const float* hw_gate_w = (const float*)d_in[34];
  const float* hw_gate_b = (const float*)d_in[35];
  const float* fc1_w = (const float*)d_in[36];
  const float* fc1_b = (const float*)d_in[37];
  const float* fc2_w = (const float*)d_in[38];
  const float* fc2_b = (const float*)d_in[39];

  float* ws = (float*)d_ws;
  float* XIN    = ws;                         // 8 * XIN_CH (reused A -> B)
  float* ATT4   = XIN;                        // alias: dead between lstmA and projB
  float* FEAT4  = XIN + 4 * BSS;
  float* HOUT_A = XIN + 8 * XIN_CH;
  float* HOUT_B = HOUT_A + 8 * HOUT_CH;
  float* MV     = HOUT_B + 8 * HOUT_CH;
  size_t needed = (size_t)((MV + 4 * MV_CH) - ws) * 4;
  if (ws_size < needed) return;

  // ---- 1. fused phase-A projections ----
  {
    Proj8 pc{};
    const int* idv[8] = {p_ids, p_ids, h_ids, h_ids, cp_ids, cp_ids, ch_ids, ch_ids};
    for (int c = 0; c < 8; ++c) {
      int word = c < 4;
      pc.c[c].ids = idv[c];
      pc.c[c].emb = word ? word_emb : char_emb;
      pc.c[c].src = nullptr;
      pc.c[c].W    = word ? ((c & 1) ? ctx_Wih_b : ctx_Wih_f) : ((c & 1) ? chr_Wih_b : chr_Wih_f);
      pc.c[c].bias = word ? ((c & 1) ? ctx_b_b : ctx_b_f)     : ((c & 1) ? chr_b_b : chr_b_f);
      pc.c[c].out = XIN + c * XIN_CH;
      pc.c[c].rev = c & 1;
      pc.c[c].K = word ? 300 : 50;
      pc.c[c].ksteps = word ? 10 : 2;
    }
    k_proj<<<8 * Sz * NBK, 256, 0, stream>>>(pc);
  }
  // ---- 2. phase-A LSTMs ----
  {
    Lstm8 la{};
    for (int c = 0; c < 8; ++c) {
      la.c[c].xin = XIN + c * XIN_CH;
      la.c[c].Whh = (c < 4) ? ((c & 1) ? ctx_Whh_b : ctx_Whh_f)
                            : ((c & 1) ? chr_Whh_b : chr_Whh_f);
      la.c[c].hout = HOUT_A + c * HOUT_CH;
      la.c[c].rev = c & 1;
      la.c[c].store_all = 1;
    }
    k_lstm<<<8, 512, 0, stream>>>(la);
  }
  // ---- 3-5. branch ----
  k_att4<<<4 * Bz * 64, 256, 0, stream>>>(HOUT_A, ATT4);
  k_feats4<<<4 * 2 * Bz * Sz, 128, 0, stream>>>(ATT4, HOUT_A, FEAT4);
  {
    MatchArgs m{};
    m.houtA = HOUT_A; m.feat4 = FEAT4; m.mv = MV;
    m.w_full[0] = mp_w1; m.w_full[1] = mp_w2; m.w_full[2] = char_w1; m.w_full[3] = char_w2;
    m.w3 = mp_w3; m.w4 = mp_w4; m.w5 = mp_w5; m.w6 = mp_w6;
    k_match24<<<4 * 6 * 160, 256, 0, stream>>>(m);
  }
  // ---- 6. phase-B projections (K=120) ----
  {
    Proj8 pa{};
    for (int c = 0; c < 8; ++c) {
      pa.c[c].ids = nullptr; pa.c[c].emb = nullptr;
      pa.c[c].src = MV + (c >> 1) * MV_CH;
      pa.c[c].W = (c & 1) ? agg_Wih_b : agg_Wih_f;
      pa.c[c].bias = (c & 1) ? agg_b_b : agg_b_f;
      pa.c[c].out = XIN + c * XIN_CH;
      pa.c[c].rev = c & 1;
      pa.c[c].K = 120;
      pa.c[c].ksteps = 4;
    }
    k_proj<<<8 * Sz * NBK, 256, 0, stream>>>(pa);
  }
  // ---- 7. phase-B LSTMs ----
  {
    Lstm8 la{};
    for (int c = 0; c < 8; ++c) {
      la.c[c].xin = XIN + c * XIN_CH;
      la.c[c].Whh = (c & 1) ? agg_Whh_b : agg_Whh_f;
      la.c[c].hout = HOUT_B + c * HOUT_CH;
      la.c[c].rev = c & 1;
      la.c[c].store_all = 0;
    }
    k_lstm<<<8, 512, 0, stream>>>(la);
  }
  // ---- 8. fused head ----
  k_head<<<Bz, 1024, 0, stream>>>(HOUT_B, hw_lin_w, hw_lin_b, hw_gate_w, hw_gate_b,
                                  fc1_w, fc1_b, fc2_w, fc2_b, (float*)d_out);
}

// Round 8
// 1195.276 us; speedup vs baseline: 3.2321x; 1.0063x over previous
//
#include <hip/hip_runtime.h>

// BiMPM on MI355X. Round 8: identical to round 7 except the per-step
// __syncthreads() in k_lstm is replaced by `s_waitcnt lgkmcnt(0); s_barrier`
// (no vmcnt drain): x prefetch loads and h stores stay in flight across the
// barrier and pipeline across steps (hipBLASLt-style), instead of being
// drained to completion 128 times.

#define Bz 16
#define Sz 128
#define Hz 100
#define Gz 400      // 4H
#define NT 25       // Gz/16 n-tiles
#define NBK 7       // ceil(25/4) n-tile blocks per t (k_proj)
#define EPSV 1e-8f

#define XIN_CH  ((long)Sz * Bz * Gz)    // 819200
#define HOUT_CH ((long)Bz * Sz * Hz)    // 204800
#define MV_CH   ((long)Bz * Sz * 120)   // 245760
#define BSS     ((long)Bz * Sz * Sz)    // 262144

typedef __attribute__((ext_vector_type(4))) float floatx4;
typedef __attribute__((ext_vector_type(8))) __bf16 bf16x8;

union FragU { bf16x8 v; unsigned u[4]; unsigned short s[8]; };

__device__ __forceinline__ float bf2f(unsigned short h) {
  unsigned u = ((unsigned)h) << 16;
  return __builtin_bit_cast(float, u);
}
__device__ __forceinline__ unsigned short f2bf(float x) {
  unsigned u = __builtin_bit_cast(unsigned, x);
  u = u + 0x7FFFu + ((u >> 16) & 1u);   // RNE
  return (unsigned short)(u >> 16);
}
__device__ __forceinline__ float sigf(float x) { return 1.0f / (1.0f + __expf(-x)); }
__device__ __forceinline__ float tanh_fast(float x) { return 1.0f - 2.0f / (__expf(2.0f * x) + 1.0f); }

// workgroup barrier that does NOT drain vmcnt: LDS-visibility only.
__device__ __forceinline__ void barrier_lds_only() {
  __asm__ __volatile__("s_waitcnt lgkmcnt(0)\ns_barrier" ::: "memory");
}

#define MFMA(a, b, c) __builtin_amdgcn_mfma_f32_16x16x32_bf16((a), (b), (c), 0, 0, 0)

__device__ __forceinline__ int pv_chain(int grp) { return (grp < 2 ? 0 : 4) + (grp & 1); }

// ---------------- projection GEMM (A=W rows, B=tokens; out[t][b][p]) ----------
// p = hidden*4+gate; W/bias rows fetched at orig = gate*Hz + hidden.
struct ProjChain {
  const int* ids;
  const float* emb;
  const float* src;
  const float* W;       // G x K fp32 (original row order)
  const float* bias;    // G fp32 (original order)
  float* out;           // S x B x G fp32: [t][b][p], gate-interleaved p
  int rev;
  int K;
  int ksteps;
};
struct Proj8 { ProjChain c[8]; };

__global__ __launch_bounds__(256) void k_proj(Proj8 P) {
  int bx = blockIdx.x;
  int c = bx / (Sz * NBK);
  int rem = bx % (Sz * NBK);
  int t = rem / NBK;
  int nb = rem % NBK;
  int wave = threadIdx.x >> 6;
  int ntile = nb * 4 + wave;
  if (ntile >= NT) return;
  int lane = threadIdx.x & 63;
  int nl = lane & 15;
  int qd = lane >> 4;

  const ProjChain ch = P.c[c];
  const int K = ch.K;
  int tp = ch.rev ? (Sz - 1 - t) : t;

  // B operand: token vector for batch nl
  const float* arow = ch.ids ? (ch.emb + (long)ch.ids[nl * Sz + tp] * K)
                             : (ch.src + ((long)nl * Sz + tp) * K);
  // A operand: W row for p = ntile*16 + nl
  int pA = ntile * 16 + nl;
  int orig_row = (pA & 3) * Hz + (pA >> 2);
  const float* wrow = ch.W + (long)orig_row * K;

  floatx4 acc = {0.f, 0.f, 0.f, 0.f};
  for (int ks = 0; ks < ch.ksteps; ++ks) {
    int k0 = ks * 32 + qd * 8;
    FragU bhi, blo, whi;
#pragma unroll
    for (int j = 0; j < 8; ++j) {
      int k = k0 + j;
      float xv = (k < K) ? arow[k] : 0.f;
      float wv = (k < K) ? wrow[k] : 0.f;
      unsigned short xh = f2bf(xv);
      bhi.s[j] = xh; blo.s[j] = f2bf(xv - bf2f(xh));
      whi.s[j] = f2bf(wv);
    }
    acc = MFMA(whi.v, bhi.v, acc);
    acc = MFMA(whi.v, blo.v, acc);
  }
  // D: row = qd*4+r = p_local, col = nl = batch
#pragma unroll
  for (int r = 0; r < 4; ++r) {
    int p = ntile * 16 + qd * 4 + r;
    acc[r] += ch.bias[(p & 3) * Hz + (p >> 2)];
  }
  *(floatx4*)(ch.out + ((long)t * Bz + nl) * Gz + ntile * 16 + qd * 4) = acc;
}

// ---------------- LSTM scan: one workgroup (8 waves) per chain ----------------
struct LstmChain {
  const float* xin;     // [t][b][p] gate-interleaved
  const float* Whh;     // G x H fp32 (original row order)
  float* hout;          // B x S x H fp32
  int rev;
  int store_all;
};
struct Lstm8 { LstmChain c[8]; };

#define NW 8      // waves per block
#define TPW 4     // max tiles per wave; tile = i*NW + w (wave 0: 4, others: 3)
#define NCH 7     // K' chunks of 32 (K'=224, valid 200)
#define HPR 232   // packed h row stride in bf16 (464B; 2-way banks only)

__global__ __launch_bounds__(512, 2) void k_lstm(Lstm8 P) {
  __shared__ __align__(16) unsigned short hpk[2][Bz * HPR];  // packed {hi,lo}
  __shared__ float hfp[2][Bz * Hz];                          // fp32 h stage

  const LstmChain ch = P.c[blockIdx.x];
  const int tid = threadIdx.x;
  const int w = tid >> 6;
  const int lane = tid & 63;
  const int nl = lane & 15;
  const int qd = lane >> 4;

  for (int i = tid; i < 2 * Bz * HPR / 2; i += 512) ((unsigned*)hpk)[i] = 0;
  __syncthreads();

  // A-operand W fragments, K'-extended (value duplicated per hi/lo k-slot)
  FragU wa[TPW][NCH];
#pragma unroll
  for (int i = 0; i < TPW; ++i) {
    int tile = i * NW + w;
    if (tile < NT) {
      int pA = tile * 16 + nl;
      const float* wr = ch.Whh + (long)((pA & 3) * Hz + (pA >> 2)) * Hz;
#pragma unroll
      for (int cc = 0; cc < NCH; ++cc) {
#pragma unroll
        for (int j = 0; j < 8; ++j) {
          int k = cc * 16 + qd * 4 + (j >> 1);
          wa[i][cc].s[j] = f2bf((k < Hz) ? wr[k] : 0.f);
        }
      }
    }
  }

  // x prefetch t=0: lane reads float4 xin[0][nl][tile*16 + qd*4]
  floatx4 xc[TPW], xn[TPW];
  float cstate[TPW];
#pragma unroll
  for (int i = 0; i < TPW; ++i) {
    cstate[i] = 0.f;
    xc[i] = floatx4{0.f, 0.f, 0.f, 0.f};
    if (i * NW + w < NT)
      xc[i] = *(const floatx4*)(ch.xin + (long)nl * Gz + (i * NW + w) * 16 + qd * 4);
  }

  for (int t = 0; t < Sz; ++t) {
    // flush h(t-1) coalesced (acks ride under the MFMA window, never drained)
    if (ch.store_all && t > 0) {
      int pb = (t - 1) & 1;
      int sprev = ch.rev ? (Sz - t) : (t - 1);
#pragma unroll
      for (int it = 0; it < 4; ++it) {
        int idx = tid + it * 512;
        if (idx < Bz * Hz)
          ch.hout[((long)(idx / Hz) * Sz + sprev) * Hz + (idx % Hz)] = hfp[pb][idx];
      }
    }
    if (t + 1 < Sz) {
      const float* xp = ch.xin + (long)(t + 1) * Bz * Gz + (long)nl * Gz;
#pragma unroll
      for (int i = 0; i < TPW; ++i)
        if (i * NW + w < NT)
          xn[i] = *(const floatx4*)(xp + (i * NW + w) * 16 + qd * 4);
    }
    const int rp = t & 1;
    floatx4 acc[TPW];
#pragma unroll
    for (int i = 0; i < TPW; ++i) acc[i] = xc[i];
#pragma unroll
    for (int cc = 0; cc < NCH; ++cc) {
      FragU bh;
      bh.v = *(const bf16x8*)(&hpk[rp][nl * HPR + cc * 32 + qd * 8]);
#pragma unroll
      for (int i = 0; i < TPW; ++i)
        if (i * NW + w < NT) acc[i] = MFMA(wa[i][cc].v, bh.v, acc[i]);
    }
    // pointwise: lane owns (batch=nl, hidden=tile*4+qd); regs = i,f,g,o
    const int wp = rp ^ 1;
    const bool keep = ch.store_all || (t == Sz - 1);
#pragma unroll
    for (int i = 0; i < TPW; ++i) {
      int tile = i * NW + w;
      if (tile < NT) {
        float cn = sigf(acc[i][1]) * cstate[i] + sigf(acc[i][0]) * tanh_fast(acc[i][2]);
        float h = sigf(acc[i][3]) * tanh_fast(cn);
        cstate[i] = cn;
        int hd = tile * 4 + qd;
        unsigned short hh = f2bf(h);
        unsigned short hl = f2bf(h - bf2f(hh));
        *(unsigned*)(&hpk[wp][nl * HPR + 2 * hd]) = (unsigned)hh | ((unsigned)hl << 16);
        if (keep) hfp[t & 1][nl * Hz + hd] = h;
      }
    }
    barrier_lds_only();   // LDS visibility only; vmem stays in flight
#pragma unroll
    for (int i = 0; i < TPW; ++i) xc[i] = xn[i];
  }
  // final h(127)
  {
    int pb = (Sz - 1) & 1;
    int slast = ch.rev ? 0 : (Sz - 1);
#pragma unroll
    for (int it = 0; it < 4; ++it) {
      int idx = tid + it * 512;
      if (idx < Bz * Hz)
        ch.hout[((long)(idx / Hz) * Sz + slast) * Hz + (idx % Hz)] = hfp[pb][idx];
    }
  }
}

// ---------------- cosine attention, 4 groups batched --------------------------
__global__ __launch_bounds__(256) void k_att4(const float* houtA, float* att4) {
  int bx = blockIdx.x;
  int grp = bx >> 10;
  int rem = bx & 1023;
  int b = rem >> 6;
  int pt = (rem >> 3) & 7;
  int qt = rem & 7;
  int pc = pv_chain(grp);
  const float* pv = houtA + (long)pc * HOUT_CH;
  const float* hv = houtA + (long)(pc + 2) * HOUT_CH;
  float* att = att4 + (long)grp * BSS;

  __shared__ float ps[16 * Hz];
  __shared__ float hs[16 * Hz];
  int tid = threadIdx.x;
  for (int i = tid; i < 16 * Hz; i += 256) {
    int r = i / Hz, h = i % Hz;
    ps[i] = pv[((long)b * Sz + pt * 16 + r) * Hz + h];
    hs[i] = hv[((long)b * Sz + qt * 16 + r) * Hz + h];
  }
  __syncthreads();
  int p = tid >> 4, q = tid & 15;
  const float* pr = &ps[p * Hz];
  const float* hr = &hs[q * Hz];
  float pq = 0.f, pp = 0.f, qq = 0.f;
#pragma unroll 4
  for (int h = 0; h < Hz; ++h) {
    float a = pr[h], bb = hr[h];
    pq += a * bb; pp += a * a; qq += bb * bb;
  }
  float denom = fmaxf(sqrtf(pp) * sqrtf(qq), EPSV);
  att[((long)b * Sz + pt * 16 + p) * Sz + qt * 16 + q] = pq / denom;
}

// ---------------- attention features, 4 groups batched ------------------------
__global__ __launch_bounds__(128) void k_feats4(const float* att4, const float* houtA,
                                                float* feat4) {
  int bx = blockIdx.x;
  int grp = bx / (2 * Bz * Sz);
  int rem = bx % (2 * Bz * Sz);
  int mode = rem / (Bz * Sz);
  int rem2 = rem % (Bz * Sz);
  int b = rem2 / Sz;
  int r = rem2 % Sz;
  int pc = pv_chain(grp);
  const float* pv = houtA + (long)pc * HOUT_CH;
  const float* hv = houtA + (long)(pc + 2) * HOUT_CH;
  const float* att = att4 + (long)grp * BSS;
  float* fb = feat4 + (long)grp * 4 * HOUT_CH;
  float* mean_h = fb;
  float* mean_p = fb + HOUT_CH;
  float* max_h  = fb + 2 * HOUT_CH;
  float* max_p  = fb + 3 * HOUT_CH;

  __shared__ float arow[Sz];
  int tid = threadIdx.x;
  if (mode == 0) arow[tid] = att[((long)b * Sz + r) * Sz + tid];
  else           arow[tid] = att[((long)b * Sz + tid) * Sz + r];
  __syncthreads();
  float asum = 0.f;
  for (int k = 0; k < Sz; ++k) asum += arow[k];
  const float* src = (mode == 0) ? hv : pv;
  if (tid < Hz) {
    float acc = 0.f, mx = -1e30f;
    for (int k = 0; k < Sz; ++k) {
      float a = arow[k];
      float v = src[((long)b * Sz + k) * Hz + tid];
      float pr = a * v;
      acc += pr;
      mx = fmaxf(mx, pr);
    }
    float mean = acc / fmaxf(asum, EPSV);
    long o = ((long)b * Sz + r) * Hz + tid;
    if (mode == 0) { mean_h[o] = mean; max_h[o] = mx; }
    else           { mean_p[o] = mean; max_p[o] = mx; }
  }
}

// ---------------- multi-perspective match, 24 instances batched ---------------
struct MatchArgs {
  const float* houtA;
  const float* feat4;
  float* mv;
  const float* w_full[4];
  const float* w3; const float* w4; const float* w5; const float* w6;
};

__global__ __launch_bounds__(256) void k_match24(MatchArgs M) {
  int bx = blockIdx.x;
  int grp = bx / (6 * 160);
  int rem = bx % (6 * 160);
  int inst = rem / 160;
  int idx = (rem % 160) * 256 + threadIdx.x;
  int l = idx % 20;
  int s = (idx / 20) % Sz;
  int b = idx / (20 * Sz);

  int fw = !(grp & 1);
  int word = grp < 2;
  int pc = pv_chain(grp);
  const float* PV = M.houtA + (long)pc * HOUT_CH;
  const float* HV = M.houtA + (long)(pc + 2) * HOUT_CH;
  const float* fb = M.feat4 + (long)grp * 4 * HOUT_CH;
  float* mvp = M.mv + (word ? 0 : 2) * MV_CH;
  float* mvh = mvp + MV_CH;
  long bc = fw ? (long)(Sz - 1) * Hz : 0;
  int off = fw ? 0 : 60;

  const float* v1; const float* v2; int v2s; const float* w; float* outb; int oo;
  switch (inst) {
    case 0: v1 = PV; v2 = HV + bc;          v2s = 0;  w = M.w_full[grp];      outb = mvp; oo = off;      break;
    case 1: v1 = PV; v2 = fb;               v2s = Hz; w = fw ? M.w3 : M.w4;   outb = mvp; oo = off + 20; break;
    case 2: v1 = PV; v2 = fb + 2 * HOUT_CH; v2s = Hz; w = fw ? M.w5 : M.w6;   outb = mvp; oo = off + 40; break;
    case 3: v1 = HV; v2 = PV + bc;          v2s = 0;  w = M.w_full[grp];      outb = mvh; oo = off;      break;
    case 4: v1 = HV; v2 = fb + HOUT_CH;     v2s = Hz; w = fw ? M.w3 : M.w4;   outb = mvh; oo = off + 20; break;
    default: v1 = HV; v2 = fb + 3 * HOUT_CH; v2s = Hz; w = fw ? M.w5 : M.w6;  outb = mvh; oo = off + 40; break;
  }
  const float* p1 = v1 + ((long)b * Sz + s) * Hz;
  const float* p2 = v2 + (long)b * Sz * Hz + (long)s * v2s;
  const float* wr = w + l * Hz;
  float num = 0.f, n1 = 0.f, n2 = 0.f;
#pragma unroll 4
  for (int h = 0; h < Hz; ++h) {
    float ww = wr[h];
    float wsq = ww * ww;
    float a = p1[h], c = p2[h];
    num += a * c * wsq;
    n1  += a * a * wsq;
    n2  += c * c * wsq;
  }
  float denom = fmaxf(sqrtf(n1) * sqrtf(n2), EPSV);
  outb[((long)b * Sz + s) * 120 + oo + l] = num / denom;
}

// ---------------- fused head -------------------------------------------------
__global__ __launch_bounds__(1024) void k_head(const float* houtB,
                                               const float* lw, const float* lb,
                                               const float* gw, const float* gb,
                                               const float* f1w, const float* f1b,
                                               const float* f2w, const float* f2b,
                                               float* out) {
  int b = blockIdx.x;
  __shared__ float xr[800];
  __shared__ float hwv[800];
  __shared__ float f1[200];
  int tid = threadIdx.x;
  if (tid < 800) {
    int seq = tid / Gz;
    int i = tid % Gz;
    int seg = i / Hz, j = i % Hz;
    int chain = seq * 4 + seg;
    int s_sel = (seg & 1) ? 0 : (Sz - 1);
    xr[tid] = houtB[((long)chain * Bz + b) * Sz * Hz + (long)s_sel * Hz + j];
  }
  __syncthreads();
  if (tid < 800) {
    int seq = tid / Gz;
    int o = tid % Gz;
    const float* xs = xr + seq * Gz;
    const float* lwr = lw + (long)o * Gz;
    const float* gwr = gw + (long)o * Gz;
    float al = 0.f, ag = 0.f;
#pragma unroll 4
    for (int k = 0; k < Gz; ++k) {
      float x = xs[k];
      al += x * lwr[k];
      ag += x * gwr[k];
    }
    al += lb[o];
    ag += gb[o];
    float hlin = fmaxf(al, 0.f);
    float tg = sigf(ag);
    hwv[tid] = tg * hlin + (1.f - tg) * xs[o];
  }
  __syncthreads();
  if (tid < 200) {
    const float* wr = f1w + (long)tid * 800;
    float acc = f1b[tid];
#pragma unroll 4
    for (int k = 0; k < 800; ++k) acc += hwv[k] * wr[k];
    f1[tid] = tanh_fast(acc);
  }
  __syncthreads();
  if (tid < 3) {
    const float* wr = f2w + tid * 200;
    float acc = f2b[tid];
    for (int k = 0; k < 200; ++k) acc += f1[k] * wr[k];
    out[b * 3 + tid] = acc;
  }
}

// ---------------- host orchestration -----------------------------------------
extern "C" void kernel_launch(void* const* d_in, const int* in_sizes, int n_in,
                              void* d_out, int out_size, void* d_ws, size_t ws_size,
                              hipStream_t stream) {
  (void)in_sizes; (void)n_in; (void)out_size;

  const int* p_ids  = (const int*)d_in[0];
  const int* h_ids  = (const int*)d_in[1];
  const int* cp_ids = (const int*)d_in[2];
  const int* ch_ids = (const int*)d_in[3];
  const float* word_emb = (const float*)d_in[4];
  const float* char_emb = (const float*)d_in[5];
  const float* ctx_Wih_f = (const float*)d_in[6];
  const float* ctx_Whh_f = (const float*)d_in[7];
  const float* ctx_b_f   = (const float*)d_in[8];
  const float* ctx_Wih_b = (const float*)d_in[9];
  const float* ctx_Whh_b = (const float*)d_in[10];
  const float* ctx_b_b   = (const float*)d_in[11];
  const float* chr_Wih_f = (const float*)d_in[12];
  const float* chr_Whh_f = (const float*)d_in[13];
  const float* chr_b_f   = (const float*)d_in[14];
  const float* chr_Wih_b = (const float*)d_in[15];
  const float* chr_Whh_b = (const float*)d_in[16];
  const float* chr_b_b   = (const float*)d_in[17];
  const float* agg_Wih_f = (const float*)d_in[18];
  const float* agg_Whh_f = (const float*)d_in[19];
  const float* agg_b_f   = (const float*)d_in[20];
  const float* agg_Wih_b = (const float*)d_in[21];
  const float* agg_Whh_b = (const float*)d_in[22];
  const float* agg_b_b   = (const float*)d_in[23];
  const float* mp_w1 = (const float*)d_in[24];
  const float* mp_w2 = (const float*)d_in[25];
  const float* mp_w3 = (const float*)d_in[26];
  const float* mp_w4 = (const float*)d_in[27];
  const float* mp_w5 = (const float*)d_in[28];
  const float* mp_w6 = (const float*)d_in[29];
  const float* char_w1 = (const float*)d_in[30];
  const float* char_w2 = (const float*)d_in[31];
  const float* hw_lin_w  = (const float*)d_in[32];
  const float* hw_lin_b  = (const float*)d_in[33];
  const float* hw_gate_w = (const float*)d_in[34];
  const float* hw_gate_b = (const float*)d_in[35];
  const float* fc1_w = (const float*)d_in[36];
  const float* fc1_b = (const float*)d_in[37];
  const float* fc2_w = (const float*)d_in[38];
  const float* fc2_b = (const float*)d_in[39];

  float* ws = (float*)d_ws;
  float* XIN    = ws;                         // 8 * XIN_CH (reused A -> B)
  float* ATT4   = XIN;                        // alias: dead between lstmA and projB
  float* FEAT4  = XIN + 4 * BSS;
  float* HOUT_A = XIN + 8 * XIN_CH;
  float* HOUT_B = HOUT_A + 8 * HOUT_CH;
  float* MV     = HOUT_B + 8 * HOUT_CH;
  size_t needed = (size_t)((MV + 4 * MV_CH) - ws) * 4;
  if (ws_size < needed) return;

  // ---- 1. fused phase-A projections ----
  {
    Proj8 pc{};
    const int* idv[8] = {p_ids, p_ids, h_ids, h_ids, cp_ids, cp_ids, ch_ids, ch_ids};
    for (int c = 0; c < 8; ++c) {
      int word = c < 4;
      pc.c[c].ids = idv[c];
      pc.c[c].emb = word ? word_emb : char_emb;
      pc.c[c].src = nullptr;
      pc.c[c].W    = word ? ((c & 1) ? ctx_Wih_b : ctx_Wih_f) : ((c & 1) ? chr_Wih_b : chr_Wih_f);
      pc.c[c].bias = word ? ((c & 1) ? ctx_b_b : ctx_b_f)     : ((c & 1) ? chr_b_b : chr_b_f);
      pc.c[c].out = XIN + c * XIN_CH;
      pc.c[c].rev = c & 1;
      pc.c[c].K = word ? 300 : 50;
      pc.c[c].ksteps = word ? 10 : 2;
    }
    k_proj<<<8 * Sz * NBK, 256, 0, stream>>>(pc);
  }
  // ---- 2. phase-A LSTMs ----
  {
    Lstm8 la{};
    for (int c = 0; c < 8; ++c) {
      la.c[c].xin = XIN + c * XIN_CH;
      la.c[c].Whh = (c < 4) ? ((c & 1) ? ctx_Whh_b : ctx_Whh_f)
                            : ((c & 1) ? chr_Whh_b : chr_Whh_f);
      la.c[c].hout = HOUT_A + c * HOUT_CH;
      la.c[c].rev = c & 1;
      la.c[c].store_all = 1;
    }
    k_lstm<<<8, 512, 0, stream>>>(la);
  }
  // ---- 3-5. branch ----
  k_att4<<<4 * Bz * 64, 256, 0, stream>>>(HOUT_A, ATT4);
  k_feats4<<<4 * 2 * Bz * Sz, 128, 0, stream>>>(ATT4, HOUT_A, FEAT4);
  {
    MatchArgs m{};
    m.houtA = HOUT_A; m.feat4 = FEAT4; m.mv = MV;
    m.w_full[0] = mp_w1; m.w_full[1] = mp_w2; m.w_full[2] = char_w1; m.w_full[3] = char_w2;
    m.w3 = mp_w3; m.w4 = mp_w4; m.w5 = mp_w5; m.w6 = mp_w6;
    k_match24<<<4 * 6 * 160, 256, 0, stream>>>(m);
  }
  // ---- 6. phase-B projections (K=120) ----
  {
    Proj8 pa{};
    for (int c = 0; c < 8; ++c) {
      pa.c[c].ids = nullptr; pa.c[c].emb = nullptr;
      pa.c[c].src = MV + (c >> 1) * MV_CH;
      pa.c[c].W = (c & 1) ? agg_Wih_b : agg_Wih_f;
      pa.c[c].bias = (c & 1) ? agg_b_b : agg_b_f;
      pa.c[c].out = XIN + c * XIN_CH;
      pa.c[c].rev = c & 1;
      pa.c[c].K = 120;
      pa.c[c].ksteps = 4;
    }
    k_proj<<<8 * Sz * NBK, 256, 0, stream>>>(pa);
  }
  // ---- 7. phase-B LSTMs ----
  {
    Lstm8 la{};
    for (int c = 0; c < 8; ++c) {
      la.c[c].xin = XIN + c * XIN_CH;
      la.c[c].Whh = (c & 1) ? agg_Whh_b : agg_Whh_f;
      la.c[c].hout = HOUT_B + c * HOUT_CH;
      la.c[c].rev = c & 1;
      la.c[c].store_all = 0;
    }
    k_lstm<<<8, 512, 0, stream>>>(la);
  }
  // ---- 8. fused head ----
  k_head<<<Bz, 1024, 0, stream>>>(HOUT_B, hw_lin_w, hw_lin_b, hw_gate_w, hw_gate_b,
                                  fc1_w, fc1_b, fc2_w, fc2_b, (float*)d_out);
}

// Round 9
// 1101.461 us; speedup vs baseline: 3.5074x; 1.0852x over previous
//
#include <hip/hip_runtime.h>

// BiMPM on MI355X. Round 9: fused branch kernel. k_att4+k_feats4+k_match24
// (and the ATT4/FEAT4 global round-trips) are replaced by k_branch: 256 blocks
// (grp x b x side x row-half), pv/hv/match-weights in LDS (~141KB), per-wave
// tasks compute att row -> mean/max feats -> 3 cosine matches with no barriers
// inside the task loop. k_lstm / k_proj untouched (ablation attribution).

#define Bz 16
#define Sz 128
#define Hz 100
#define Gz 400      // 4H
#define NT 25       // Gz/16 n-tiles
#define NBK 7       // ceil(25/4) n-tile blocks per t (k_proj)
#define EPSV 1e-8f

#define XIN_CH  ((long)Sz * Bz * Gz)    // 819200
#define HOUT_CH ((long)Bz * Sz * Hz)    // 204800
#define MV_CH   ((long)Bz * Sz * 120)   // 245760

typedef __attribute__((ext_vector_type(4))) float floatx4;
typedef __attribute__((ext_vector_type(8))) __bf16 bf16x8;

union FragU { bf16x8 v; unsigned u[4]; unsigned short s[8]; };

__device__ __forceinline__ float bf2f(unsigned short h) {
  unsigned u = ((unsigned)h) << 16;
  return __builtin_bit_cast(float, u);
}
__device__ __forceinline__ unsigned short f2bf(float x) {
  unsigned u = __builtin_bit_cast(unsigned, x);
  u = u + 0x7FFFu + ((u >> 16) & 1u);   // RNE
  return (unsigned short)(u >> 16);
}
__device__ __forceinline__ float sigf(float x) { return 1.0f / (1.0f + __expf(-x)); }
__device__ __forceinline__ float tanh_fast(float x) { return 1.0f - 2.0f / (__expf(2.0f * x) + 1.0f); }

// workgroup barrier that does NOT drain vmcnt: LDS-visibility only.
__device__ __forceinline__ void barrier_lds_only() {
  __asm__ __volatile__("s_waitcnt lgkmcnt(0)\ns_barrier" ::: "memory");
}

#define MFMA(a, b, c) __builtin_amdgcn_mfma_f32_16x16x32_bf16((a), (b), (c), 0, 0, 0)

__device__ __forceinline__ int pv_chain(int grp) { return (grp < 2 ? 0 : 4) + (grp & 1); }

// ---------------- projection GEMM (A=W rows, B=tokens; out[t][b][p]) ----------
struct ProjChain {
  const int* ids;
  const float* emb;
  const float* src;
  const float* W;       // G x K fp32 (original row order)
  const float* bias;    // G fp32 (original order)
  float* out;           // S x B x G fp32: [t][b][p], gate-interleaved p
  int rev;
  int K;
  int ksteps;
};
struct Proj8 { ProjChain c[8]; };

__global__ __launch_bounds__(256) void k_proj(Proj8 P) {
  int bx = blockIdx.x;
  int c = bx / (Sz * NBK);
  int rem = bx % (Sz * NBK);
  int t = rem / NBK;
  int nb = rem % NBK;
  int wave = threadIdx.x >> 6;
  int ntile = nb * 4 + wave;
  if (ntile >= NT) return;
  int lane = threadIdx.x & 63;
  int nl = lane & 15;
  int qd = lane >> 4;

  const ProjChain ch = P.c[c];
  const int K = ch.K;
  int tp = ch.rev ? (Sz - 1 - t) : t;

  const float* arow = ch.ids ? (ch.emb + (long)ch.ids[nl * Sz + tp] * K)
                             : (ch.src + ((long)nl * Sz + tp) * K);
  int pA = ntile * 16 + nl;
  int orig_row = (pA & 3) * Hz + (pA >> 2);
  const float* wrow = ch.W + (long)orig_row * K;

  floatx4 acc = {0.f, 0.f, 0.f, 0.f};
  for (int ks = 0; ks < ch.ksteps; ++ks) {
    int k0 = ks * 32 + qd * 8;
    FragU bhi, blo, whi;
#pragma unroll
    for (int j = 0; j < 8; ++j) {
      int k = k0 + j;
      float xv = (k < K) ? arow[k] : 0.f;
      float wv = (k < K) ? wrow[k] : 0.f;
      unsigned short xh = f2bf(xv);
      bhi.s[j] = xh; blo.s[j] = f2bf(xv - bf2f(xh));
      whi.s[j] = f2bf(wv);
    }
    acc = MFMA(whi.v, bhi.v, acc);
    acc = MFMA(whi.v, blo.v, acc);
  }
#pragma unroll
  for (int r = 0; r < 4; ++r) {
    int p = ntile * 16 + qd * 4 + r;
    acc[r] += ch.bias[(p & 3) * Hz + (p >> 2)];
  }
  *(floatx4*)(ch.out + ((long)t * Bz + nl) * Gz + ntile * 16 + qd * 4) = acc;
}

// ---------------- LSTM scan: one workgroup (8 waves) per chain ----------------
struct LstmChain {
  const float* xin;     // [t][b][p] gate-interleaved
  const float* Whh;     // G x H fp32 (original row order)
  float* hout;          // B x S x H fp32
  int rev;
  int store_all;
};
struct Lstm8 { LstmChain c[8]; };

#define NW 8      // waves per block
#define TPW 4     // max tiles per wave; tile = i*NW + w
#define NCH 7     // K' chunks of 32 (K'=224, valid 200)
#define HPR 232   // packed h row stride in bf16

__global__ __launch_bounds__(512, 2) void k_lstm(Lstm8 P) {
  __shared__ __align__(16) unsigned short hpk[2][Bz * HPR];  // packed {hi,lo}
  __shared__ float hfp[2][Bz * Hz];                          // fp32 h stage

  const LstmChain ch = P.c[blockIdx.x];
  const int tid = threadIdx.x;
  const int w = tid >> 6;
  const int lane = tid & 63;
  const int nl = lane & 15;
  const int qd = lane >> 4;

  for (int i = tid; i < 2 * Bz * HPR / 2; i += 512) ((unsigned*)hpk)[i] = 0;
  __syncthreads();

  FragU wa[TPW][NCH];
#pragma unroll
  for (int i = 0; i < TPW; ++i) {
    int tile = i * NW + w;
    if (tile < NT) {
      int pA = tile * 16 + nl;
      const float* wr = ch.Whh + (long)((pA & 3) * Hz + (pA >> 2)) * Hz;
#pragma unroll
      for (int cc = 0; cc < NCH; ++cc) {
#pragma unroll
        for (int j = 0; j < 8; ++j) {
          int k = cc * 16 + qd * 4 + (j >> 1);
          wa[i][cc].s[j] = f2bf((k < Hz) ? wr[k] : 0.f);
        }
      }
    }
  }

  floatx4 xc[TPW], xn[TPW];
  float cstate[TPW];
#pragma unroll
  for (int i = 0; i < TPW; ++i) {
    cstate[i] = 0.f;
    xc[i] = floatx4{0.f, 0.f, 0.f, 0.f};
    if (i * NW + w < NT)
      xc[i] = *(const floatx4*)(ch.xin + (long)nl * Gz + (i * NW + w) * 16 + qd * 4);
  }

  for (int t = 0; t < Sz; ++t) {
    if (ch.store_all && t > 0) {
      int pb = (t - 1) & 1;
      int sprev = ch.rev ? (Sz - t) : (t - 1);
#pragma unroll
      for (int it = 0; it < 4; ++it) {
        int idx = tid + it * 512;
        if (idx < Bz * Hz)
          ch.hout[((long)(idx / Hz) * Sz + sprev) * Hz + (idx % Hz)] = hfp[pb][idx];
      }
    }
    if (t + 1 < Sz) {
      const float* xp = ch.xin + (long)(t + 1) * Bz * Gz + (long)nl * Gz;
#pragma unroll
      for (int i = 0; i < TPW; ++i)
        if (i * NW + w < NT)
          xn[i] = *(const floatx4*)(xp + (i * NW + w) * 16 + qd * 4);
    }
    const int rp = t & 1;
    floatx4 acc[TPW];
#pragma unroll
    for (int i = 0; i < TPW; ++i) acc[i] = xc[i];
#pragma unroll
    for (int cc = 0; cc < NCH; ++cc) {
      FragU bh;
      bh.v = *(const bf16x8*)(&hpk[rp][nl * HPR + cc * 32 + qd * 8]);
#pragma unroll
      for (int i = 0; i < TPW; ++i)
        if (i * NW + w < NT) acc[i] = MFMA(wa[i][cc].v, bh.v, acc[i]);
    }
    const int wp = rp ^ 1;
    const bool keep = ch.store_all || (t == Sz - 1);
#pragma unroll
    for (int i = 0; i < TPW; ++i) {
      int tile = i * NW + w;
      if (tile < NT) {
        float cn = sigf(acc[i][1]) * cstate[i] + sigf(acc[i][0]) * tanh_fast(acc[i][2]);
        float h = sigf(acc[i][3]) * tanh_fast(cn);
        cstate[i] = cn;
        int hd = tile * 4 + qd;
        unsigned short hh = f2bf(h);
        unsigned short hl = f2bf(h - bf2f(hh));
        *(unsigned*)(&hpk[wp][nl * HPR + 2 * hd]) = (unsigned)hh | ((unsigned)hl << 16);
        if (keep) hfp[t & 1][nl * Hz + hd] = h;
      }
    }
    barrier_lds_only();
#pragma unroll
    for (int i = 0; i < TPW; ++i) xc[i] = xn[i];
  }
  {
    int pb = (Sz - 1) & 1;
    int slast = ch.rev ? 0 : (Sz - 1);
#pragma unroll
    for (int it = 0; it < 4; ++it) {
      int idx = tid + it * 512;
      if (idx < Bz * Hz)
        ch.hout[((long)(idx / Hz) * Sz + slast) * Hz + (idx % Hz)] = hfp[pb][idx];
    }
  }
}

// ---------------- fused branch: att + feats + match, one kernel ---------------
// 256 blocks: grp(4) x b(16) x side(2) x row-half(2). 512 threads, ~141KB LDS.
#define PVS2 102   // padded row stride (floats); 8B-aligned rows, 2-way banks
#define FS 104     // feat scratch stride

struct BranchArgs {
  const float* houtA;
  float* mv;
  const float* w_full[4];
  const float* w3; const float* w4; const float* w5; const float* w6;
};

__global__ __launch_bounds__(512, 1) void k_branch(BranchArgs G) {
  __shared__ float pvs[128 * PVS2];
  __shared__ float hvs[128 * PVS2 + 32];   // +pad: feats j+64 lane overread
  __shared__ float wl[60 * PVS2];
  __shared__ float attw[8 * 128];
  __shared__ float fmean[8 * FS];
  __shared__ float fmax[8 * FS];
  __shared__ float nrmp[128], nrmh[128];

  int bx = blockIdx.x;
  int grp = bx >> 6;
  int b = (bx >> 2) & 15;
  int side = (bx >> 1) & 1;
  int rh = bx & 1;
  int fw = !(grp & 1);
  int word = grp < 2;
  int pc = pv_chain(grp);
  const float* PV = G.houtA + (long)pc * HOUT_CH + (long)b * Sz * Hz;
  const float* HV = G.houtA + (long)(pc + 2) * HOUT_CH + (long)b * Sz * Hz;
  int tid = threadIdx.x;
  int w = tid >> 6, lane = tid & 63;

  // phase 0: stage pv, hv, match weights
  for (int i = tid; i < 128 * Hz; i += 512) {
    int r = i / Hz, c = i % Hz;
    pvs[r * PVS2 + c] = PV[r * Hz + c];
    hvs[r * PVS2 + c] = HV[r * Hz + c];
  }
  {
    const float* wm = fw ? G.w3 : G.w4;
    const float* wx = fw ? G.w5 : G.w6;
    const float* wf = G.w_full[grp];
    for (int i = tid; i < 60 * Hz; i += 512) {
      int row = i / Hz, c = i % Hz;
      const float* src = (row < 20) ? wf : (row < 40 ? wm : wx);
      int rr = (row < 20) ? row : (row < 40 ? row - 20 : row - 40);
      wl[row * PVS2 + c] = src[rr * Hz + c];
    }
  }
  __syncthreads();
  // phase 0b: row norms
  if (tid < 256) {
    const float* base = (tid < 128) ? pvs : hvs;
    int r = tid & 127;
    float s = 0.f;
    for (int j = 0; j < Hz; ++j) { float v = base[r * PVS2 + j]; s += v * v; }
    if (tid < 128) nrmp[r] = sqrtf(s); else nrmh[r] = sqrtf(s);
  }
  __syncthreads();

  const float* A  = side ? hvs : pvs;
  const float* B  = side ? pvs : hvs;
  const float* nA = side ? nrmh : nrmp;
  const float* nB = side ? nrmp : nrmh;
  int bcrow = fw ? (Sz - 1) : 0;
  float* mvout = G.mv + (long)((word ? 0 : 2) + side) * MV_CH + (long)b * Sz * 120;
  int off = fw ? 0 : 60;
  int type = lane / 20;                 // 0 full, 1 mean, 2 max (lanes 0..59)
  const float* wrow = wl + lane * PVS2;
  float* myatt = attw + w * 128;
  float* myfm = fmean + w * FS;
  float* myfx = fmax + w * FS;

  for (int task = w; task < 64; task += 8) {
    int r = rh * 64 + task;
    const float* ar = A + r * PVS2;
    // --- att row: lane owns cols q=lane, q+64 ---
    float d0 = 0.f, d1 = 0.f;
    const float* b0 = B + lane * PVS2;
    const float* b1 = B + (lane + 64) * PVS2;
    for (int j = 0; j < Hz; j += 2) {
      float2 a2 = *(const float2*)(ar + j);
      float2 p2 = *(const float2*)(b0 + j);
      float2 q2 = *(const float2*)(b1 + j);
      d0 += a2.x * p2.x + a2.y * p2.y;
      d1 += a2.x * q2.x + a2.y * q2.y;
    }
    float at0 = d0 / fmaxf(nA[r] * nB[lane], EPSV);
    float at1 = d1 / fmaxf(nA[r] * nB[lane + 64], EPSV);
    myatt[lane] = at0;
    myatt[lane + 64] = at1;
    float s = at0 + at1;
#pragma unroll
    for (int m = 1; m < 64; m <<= 1) s += __shfl_xor(s, m);
    float inv = 1.f / fmaxf(s, EPSV);
    // --- feats: lane owns feature dims j=lane (and j+64 when valid) ---
    float m0 = 0.f, m1 = 0.f, x0 = -1e30f, x1 = -1e30f;
    const float* bj0 = B + lane;
    const float* bj1 = B + lane + 64;
    for (int q = 0; q < 128; ++q) {
      float aq = myatt[q];
      float v0 = bj0[q * PVS2];
      float v1 = bj1[q * PVS2];
      m0 += aq * v0; x0 = fmaxf(x0, aq * v0);
      m1 += aq * v1; x1 = fmaxf(x1, aq * v1);
    }
    myfm[lane] = m0 * inv;
    myfx[lane] = x0;
    if (lane < Hz - 64) { myfm[lane + 64] = m1 * inv; myfx[lane + 64] = x1; }
    // --- match: lanes 0..59 = (type, l) ---
    if (lane < 60) {
      const float* v2p = (type == 0) ? (B + bcrow * PVS2)
                       : (type == 1) ? myfm : myfx;
      float num = 0.f, n1 = 0.f, n2 = 0.f;
      for (int j = 0; j < Hz; j += 2) {
        float2 w2 = *(const float2*)(wrow + j);
        float2 a2 = *(const float2*)(ar + j);
        float2 c2 = *(const float2*)(v2p + j);
        float ws0 = w2.x * w2.x, ws1 = w2.y * w2.y;
        num += ws0 * a2.x * c2.x + ws1 * a2.y * c2.y;
        n1  += ws0 * a2.x * a2.x + ws1 * a2.y * a2.y;
        n2  += ws0 * c2.x * c2.x + ws1 * c2.y * c2.y;
      }
      mvout[r * 120 + off + lane] = num / fmaxf(sqrtf(n1) * sqrtf(n2), EPSV);
    }
  }
}

// ---------------- fused head -------------------------------------------------
__global__ __launch_bounds__(1024) void k_head(const float* houtB,
                                               const float* lw, const float* lb,
                                               const float* gw, const float* gb,
                                               const float* f1w, const float* f1b,
                                               const float* f2w, const float* f2b,
                                               float* out) {
  int b = blockIdx.x;
  __shared__ float xr[800];
  __shared__ float hwv[800];
  __shared__ float f1[200];
  int tid = threadIdx.x;
  if (tid < 800) {
    int seq = tid / Gz;
    int i = tid % Gz;
    int seg = i / Hz, j = i % Hz;
    int chain = seq * 4 + seg;
    int s_sel = (seg & 1) ? 0 : (Sz - 1);
    xr[tid] = houtB[((long)chain * Bz + b) * Sz * Hz + (long)s_sel * Hz + j];
  }
  __syncthreads();
  if (tid < 800) {
    int seq = tid / Gz;
    int o = tid % Gz;
    const float* xs = xr + seq * Gz;
    const float* lwr = lw + (long)o * Gz;
    const float* gwr = gw + (long)o * Gz;
    float al = 0.f, ag = 0.f;
#pragma unroll 4
    for (int k = 0; k < Gz; ++k) {
      float x = xs[k];
      al += x * lwr[k];
      ag += x * gwr[k];
    }
    al += lb[o];
    ag += gb[o];
    float hlin = fmaxf(al, 0.f);
    float tg = sigf(ag);
    hwv[tid] = tg * hlin + (1.f - tg) * xs[o];
  }
  __syncthreads();
  if (tid < 200) {
    const float* wr = f1w + (long)tid * 800;
    float acc = f1b[tid];
#pragma unroll 4
    for (int k = 0; k < 800; ++k) acc += hwv[k] * wr[k];
    f1[tid] = tanh_fast(acc);
  }
  __syncthreads();
  if (tid < 3) {
    const float* wr = f2w + tid * 200;
    float acc = f2b[tid];
    for (int k = 0; k < 200; ++k) acc += f1[k] * wr[k];
    out[b * 3 + tid] = acc;
  }
}

// ---------------- host orchestration -----------------------------------------
extern "C" void kernel_launch(void* const* d_in, const int* in_sizes, int n_in,
                              void* d_out, int out_size, void* d_ws, size_t ws_size,
                              hipStream_t stream) {
  (void)in_sizes; (void)n_in; (void)out_size;

  const int* p_ids  = (const int*)d_in[0];
  const int* h_ids  = (const int*)d_in[1];
  const int* cp_ids = (const int*)d_in[2];
  const int* ch_ids = (const int*)d_in[3];
  const float* word_emb = (const float*)d_in[4];
  const float* char_emb = (const float*)d_in[5];
  const float* ctx_Wih_f = (const float*)d_in[6];
  const float* ctx_Whh_f = (const float*)d_in[7];
  const float* ctx_b_f   = (const float*)d_in[8];
  const float* ctx_Wih_b = (const float*)d_in[9];
  const float* ctx_Whh_b = (const float*)d_in[10];
  const float* ctx_b_b   = (const float*)d_in[11];
  const float* chr_Wih_f = (const float*)d_in[12];
  const float* chr_Whh_f = (const float*)d_in[13];
  const float* chr_b_f   = (const float*)d_in[14];
  const float* chr_Wih_b = (const float*)d_in[15];
  const float* chr_Whh_b = (const float*)d_in[16];
  const float* chr_b_b   = (const float*)d_in[17];
  const float* agg_Wih_f = (const float*)d_in[18];
  const float* agg_Whh_f = (const float*)d_in[19];
  const float* agg_b_f   = (const float*)d_in[20];
  const float* agg_Wih_b = (const float*)d_in[21];
  const float* agg_Whh_b = (const float*)d_in[22];
  const float* agg_b_b   = (const float*)d_in[23];
  const float* mp_w1 = (const float*)d_in[24];
  const float* mp_w2 = (const float*)d_in[25];
  const float* mp_w3 = (const float*)d_in[26];
  const float* mp_w4 = (const float*)d_in[27];
  const float* mp_w5 = (const float*)d_in[28];
  const float* mp_w6 = (const float*)d_in[29];
  const float* char_w1 = (const float*)d_in[30];
  const float* char_w2 = (const float*)d_in[31];
  const float* hw_lin_w  = (const float*)d_in[32];
  const float* hw_lin_b  = (const float*)d_in[33];
  const float* hw_gate_w = (const float*)d_in[34];
  const float* hw_gate_b = (const float*)d_in[35];
  const float* fc1_w = (const float*)d_in[36];
  const float* fc1_b = (const float*)d_in[37];
  const float* fc2_w = (const float*)d_in[38];
  const float* fc2_b = (const float*)d_in[39];

  float* ws = (float*)d_ws;
  float* XIN    = ws;                         // 8 * XIN_CH (reused A -> B)
  float* HOUT_A = XIN + 8 * XIN_CH;
  float* HOUT_B = HOUT_A + 8 * HOUT_CH;
  float* MV     = HOUT_B + 8 * HOUT_CH;
  size_t needed = (size_t)((MV + 4 * MV_CH) - ws) * 4;
  if (ws_size < needed) return;

  // ---- 1. fused phase-A projections ----
  {
    Proj8 pc{};
    const int* idv[8] = {p_ids, p_ids, h_ids, h_ids, cp_ids, cp_ids, ch_ids, ch_ids};
    for (int c = 0; c < 8; ++c) {
      int word = c < 4;
      pc.c[c].ids = idv[c];
      pc.c[c].emb = word ? word_emb : char_emb;
      pc.c[c].src = nullptr;
      pc.c[c].W    = word ? ((c & 1) ? ctx_Wih_b : ctx_Wih_f) : ((c & 1) ? chr_Wih_b : chr_Wih_f);
      pc.c[c].bias = word ? ((c & 1) ? ctx_b_b : ctx_b_f)     : ((c & 1) ? chr_b_b : chr_b_f);
      pc.c[c].out = XIN + c * XIN_CH;
      pc.c[c].rev = c & 1;
      pc.c[c].K = word ? 300 : 50;
      pc.c[c].ksteps = word ? 10 : 2;
    }
    k_proj<<<8 * Sz * NBK, 256, 0, stream>>>(pc);
  }
  // ---- 2. phase-A LSTMs ----
  {
    Lstm8 la{};
    for (int c = 0; c < 8; ++c) {
      la.c[c].xin = XIN + c * XIN_CH;
      la.c[c].Whh = (c < 4) ? ((c & 1) ? ctx_Whh_b : ctx_Whh_f)
                            : ((c & 1) ? chr_Whh_b : chr_Whh_f);
      la.c[c].hout = HOUT_A + c * HOUT_CH;
      la.c[c].rev = c & 1;
      la.c[c].store_all = 1;
    }
    k_lstm<<<8, 512, 0, stream>>>(la);
  }
  // ---- 3. fused branch ----
  {
    BranchArgs g{};
    g.houtA = HOUT_A; g.mv = MV;
    g.w_full[0] = mp_w1; g.w_full[1] = mp_w2; g.w_full[2] = char_w1; g.w_full[3] = char_w2;
    g.w3 = mp_w3; g.w4 = mp_w4; g.w5 = mp_w5; g.w6 = mp_w6;
    k_branch<<<256, 512, 0, stream>>>(g);
  }
  // ---- 4. phase-B projections (K=120) ----
  {
    Proj8 pa{};
    for (int c = 0; c < 8; ++c) {
      pa.c[c].ids = nullptr; pa.c[c].emb = nullptr;
      pa.c[c].src = MV + (c >> 1) * MV_CH;
      pa.c[c].W = (c & 1) ? agg_Wih_b : agg_Wih_f;
      pa.c[c].bias = (c & 1) ? agg_b_b : agg_b_f;
      pa.c[c].out = XIN + c * XIN_CH;
      pa.c[c].rev = c & 1;
      pa.c[c].K = 120;
      pa.c[c].ksteps = 4;
    }
    k_proj<<<8 * Sz * NBK, 256, 0, stream>>>(pa);
  }
  // ---- 5. phase-B LSTMs ----
  {
    Lstm8 la{};
    for (int c = 0; c < 8; ++c) {
      la.c[c].xin = XIN + c * XIN_CH;
      la.c[c].Whh = (c & 1) ? agg_Whh_b : agg_Whh_f;
      la.c[c].hout = HOUT_B + c * HOUT_CH;
      la.c[c].rev = c & 1;
      la.c[c].store_all = 0;
    }
    k_lstm<<<8, 512, 0, stream>>>(la);
  }
  // ---- 6. fused head ----
  k_head<<<Bz, 1024, 0, stream>>>(HOUT_B, hw_lin_w, hw_lin_b, hw_gate_w, hw_gate_b,
                                  fc1_w, fc1_b, fc2_w, fc2_b, (float*)d_out);
}

// Round 10
// 948.497 us; speedup vs baseline: 4.0731x; 1.1613x over previous
//
#include <hip/hip_runtime.h>

// BiMPM on MI355X. Round 10: k_proj restructured — one block per (chain,t),
// token rows staged ONCE into LDS as packed bf16 hi/lo (old version re-fetched
// tokens per n-tile block: ~2GB of L2/L3 re-read traffic = the hidden ~560us).
// B-frags hoisted per K-chunk (reused by all 7 tiles of a wave); W streamed
// from L2 once per (c,t). k_lstm / k_branch / k_head unchanged.

#define Bz 16
#define Sz 128
#define Hz 100
#define Gz 400      // 4H
#define NT 25       // Gz/16 n-tiles
#define EPSV 1e-8f

#define XIN_CH  ((long)Sz * Bz * Gz)    // 819200
#define HOUT_CH ((long)Bz * Sz * Hz)    // 204800
#define MV_CH   ((long)Bz * Sz * 120)   // 245760

typedef __attribute__((ext_vector_type(4))) float floatx4;
typedef __attribute__((ext_vector_type(8))) __bf16 bf16x8;

union FragU { bf16x8 v; unsigned u[4]; unsigned short s[8]; };

__device__ __forceinline__ float bf2f(unsigned short h) {
  unsigned u = ((unsigned)h) << 16;
  return __builtin_bit_cast(float, u);
}
__device__ __forceinline__ unsigned short f2bf(float x) {
  unsigned u = __builtin_bit_cast(unsigned, x);
  u = u + 0x7FFFu + ((u >> 16) & 1u);   // RNE
  return (unsigned short)(u >> 16);
}
__device__ __forceinline__ float sigf(float x) { return 1.0f / (1.0f + __expf(-x)); }
__device__ __forceinline__ float tanh_fast(float x) { return 1.0f - 2.0f / (__expf(2.0f * x) + 1.0f); }

// workgroup barrier that does NOT drain vmcnt: LDS-visibility only.
__device__ __forceinline__ void barrier_lds_only() {
  __asm__ __volatile__("s_waitcnt lgkmcnt(0)\ns_barrier" ::: "memory");
}

#define MFMA(a, b, c) __builtin_amdgcn_mfma_f32_16x16x32_bf16((a), (b), (c), 0, 0, 0)

__device__ __forceinline__ int pv_chain(int grp) { return (grp < 2 ? 0 : 4) + (grp & 1); }

// ---------------- projection GEMM: block per (chain,t), LDS-staged tokens -----
// out[t][b][p], p = hidden*4+gate; W/bias rows at orig = (p&3)*Hz + (p>>2).
struct ProjChain {
  const int* ids;
  const float* emb;
  const float* src;
  const float* W;       // G x K fp32 (original row order)
  const float* bias;    // G fp32 (original order)
  float* out;           // [t][b][p] fp32, gate-interleaved p
  int rev;
  int K;
  int nch;              // ceil(K/32)
};
struct Proj8 { ProjChain c[8]; };

#define PPS 328   // staged token row stride in ushort (656B: 16B-mult, bank-spread)

__global__ __launch_bounds__(256) void k_proj(Proj8 P) {
  __shared__ __align__(16) unsigned short phi[16 * PPS];
  __shared__ __align__(16) unsigned short plo[16 * PPS];

  int bx = blockIdx.x;
  int c = bx >> 7;
  int t = bx & 127;
  const ProjChain ch = P.c[c];
  const int K = ch.K;
  const int KP = ch.nch * 32;
  int tp = ch.rev ? (Sz - 1 - t) : t;
  int tid = threadIdx.x;

  // stage tokens once: fp32 -> packed bf16 hi/lo
  for (int i = tid; i < 16 * KP; i += 256) {
    int b = i / KP, k = i % KP;
    float v = 0.f;
    if (k < K) {
      const float* row = ch.ids ? (ch.emb + (long)ch.ids[b * Sz + tp] * K)
                                : (ch.src + ((long)b * Sz + tp) * K);
      v = row[k];
    }
    unsigned short hh = f2bf(v);
    phi[b * PPS + k] = hh;
    plo[b * PPS + k] = f2bf(v - bf2f(hh));
  }
  __syncthreads();

  int w = tid >> 6, lane = tid & 63;
  int nl = lane & 15, qd = lane >> 4;
  floatx4 acc[7];
#pragma unroll
  for (int i = 0; i < 7; ++i) acc[i] = floatx4{0.f, 0.f, 0.f, 0.f};

  for (int cc = 0; cc < ch.nch; ++cc) {
    FragU bhi, blo;
    bhi.v = *(const bf16x8*)&phi[nl * PPS + cc * 32 + qd * 8];
    blo.v = *(const bf16x8*)&plo[nl * PPS + cc * 32 + qd * 8];
#pragma unroll
    for (int i = 0; i < 7; ++i) {
      int nt = w + 4 * i;
      if (nt < NT) {
        int pA = nt * 16 + nl;
        const float* wrow = ch.W + (long)((pA & 3) * Hz + (pA >> 2)) * K;
        FragU whi;
#pragma unroll
        for (int j = 0; j < 8; ++j) {
          int k = cc * 32 + qd * 8 + j;
          whi.s[j] = f2bf((k < K) ? wrow[k] : 0.f);
        }
        acc[i] = MFMA(whi.v, bhi.v, acc[i]);
        acc[i] = MFMA(whi.v, blo.v, acc[i]);
      }
    }
  }
#pragma unroll
  for (int i = 0; i < 7; ++i) {
    int nt = w + 4 * i;
    if (nt < NT) {
#pragma unroll
      for (int r = 0; r < 4; ++r) {
        int p = nt * 16 + qd * 4 + r;
        acc[i][r] += ch.bias[(p & 3) * Hz + (p >> 2)];
      }
      *(floatx4*)(ch.out + ((long)t * Bz + nl) * Gz + nt * 16 + qd * 4) = acc[i];
    }
  }
}

// ---------------- LSTM scan: one workgroup (8 waves) per chain ----------------
struct LstmChain {
  const float* xin;     // [t][b][p] gate-interleaved
  const float* Whh;     // G x H fp32 (original row order)
  float* hout;          // B x S x H fp32
  int rev;
  int store_all;
};
struct Lstm8 { LstmChain c[8]; };

#define NW 8      // waves per block
#define TPW 4     // max tiles per wave; tile = i*NW + w
#define NCH 7     // K' chunks of 32 (K'=224, valid 200)
#define HPR 232   // packed h row stride in bf16

__global__ __launch_bounds__(512, 2) void k_lstm(Lstm8 P) {
  __shared__ __align__(16) unsigned short hpk[2][Bz * HPR];  // packed {hi,lo}
  __shared__ float hfp[2][Bz * Hz];                          // fp32 h stage

  const LstmChain ch = P.c[blockIdx.x];
  const int tid = threadIdx.x;
  const int w = tid >> 6;
  const int lane = tid & 63;
  const int nl = lane & 15;
  const int qd = lane >> 4;

  for (int i = tid; i < 2 * Bz * HPR / 2; i += 512) ((unsigned*)hpk)[i] = 0;
  __syncthreads();

  FragU wa[TPW][NCH];
#pragma unroll
  for (int i = 0; i < TPW; ++i) {
    int tile = i * NW + w;
    if (tile < NT) {
      int pA = tile * 16 + nl;
      const float* wr = ch.Whh + (long)((pA & 3) * Hz + (pA >> 2)) * Hz;
#pragma unroll
      for (int cc = 0; cc < NCH; ++cc) {
#pragma unroll
        for (int j = 0; j < 8; ++j) {
          int k = cc * 16 + qd * 4 + (j >> 1);
          wa[i][cc].s[j] = f2bf((k < Hz) ? wr[k] : 0.f);
        }
      }
    }
  }

  floatx4 xc[TPW], xn[TPW];
  float cstate[TPW];
#pragma unroll
  for (int i = 0; i < TPW; ++i) {
    cstate[i] = 0.f;
    xc[i] = floatx4{0.f, 0.f, 0.f, 0.f};
    if (i * NW + w < NT)
      xc[i] = *(const floatx4*)(ch.xin + (long)nl * Gz + (i * NW + w) * 16 + qd * 4);
  }

  for (int t = 0; t < Sz; ++t) {
    if (ch.store_all && t > 0) {
      int pb = (t - 1) & 1;
      int sprev = ch.rev ? (Sz - t) : (t - 1);
#pragma unroll
      for (int it = 0; it < 4; ++it) {
        int idx = tid + it * 512;
        if (idx < Bz * Hz)
          ch.hout[((long)(idx / Hz) * Sz + sprev) * Hz + (idx % Hz)] = hfp[pb][idx];
      }
    }
    if (t + 1 < Sz) {
      const float* xp = ch.xin + (long)(t + 1) * Bz * Gz + (long)nl * Gz;
#pragma unroll
      for (int i = 0; i < TPW; ++i)
        if (i * NW + w < NT)
          xn[i] = *(const floatx4*)(xp + (i * NW + w) * 16 + qd * 4);
    }
    const int rp = t & 1;
    floatx4 acc[TPW];
#pragma unroll
    for (int i = 0; i < TPW; ++i) acc[i] = xc[i];
#pragma unroll
    for (int cc = 0; cc < NCH; ++cc) {
      FragU bh;
      bh.v = *(const bf16x8*)(&hpk[rp][nl * HPR + cc * 32 + qd * 8]);
#pragma unroll
      for (int i = 0; i < TPW; ++i)
        if (i * NW + w < NT) acc[i] = MFMA(wa[i][cc].v, bh.v, acc[i]);
    }
    const int wp = rp ^ 1;
    const bool keep = ch.store_all || (t == Sz - 1);
#pragma unroll
    for (int i = 0; i < TPW; ++i) {
      int tile = i * NW + w;
      if (tile < NT) {
        float cn = sigf(acc[i][1]) * cstate[i] + sigf(acc[i][0]) * tanh_fast(acc[i][2]);
        float h = sigf(acc[i][3]) * tanh_fast(cn);
        cstate[i] = cn;
        int hd = tile * 4 + qd;
        unsigned short hh = f2bf(h);
        unsigned short hl = f2bf(h - bf2f(hh));
        *(unsigned*)(&hpk[wp][nl * HPR + 2 * hd]) = (unsigned)hh | ((unsigned)hl << 16);
        if (keep) hfp[t & 1][nl * Hz + hd] = h;
      }
    }
    barrier_lds_only();
#pragma unroll
    for (int i = 0; i < TPW; ++i) xc[i] = xn[i];
  }
  {
    int pb = (Sz - 1) & 1;
    int slast = ch.rev ? 0 : (Sz - 1);
#pragma unroll
    for (int it = 0; it < 4; ++it) {
      int idx = tid + it * 512;
      if (idx < Bz * Hz)
        ch.hout[((long)(idx / Hz) * Sz + slast) * Hz + (idx % Hz)] = hfp[pb][idx];
    }
  }
}

// ---------------- fused branch: att + feats + match, one kernel ---------------
#define PVS2 102   // padded row stride (floats)
#define FS 104     // feat scratch stride

struct BranchArgs {
  const float* houtA;
  float* mv;
  const float* w_full[4];
  const float* w3; const float* w4; const float* w5; const float* w6;
};

__global__ __launch_bounds__(512, 1) void k_branch(BranchArgs G) {
  __shared__ float pvs[128 * PVS2];
  __shared__ float hvs[128 * PVS2 + 32];   // +pad: feats j+64 lane overread
  __shared__ float wl[60 * PVS2];
  __shared__ float attw[8 * 128];
  __shared__ float fmean[8 * FS];
  __shared__ float fmax[8 * FS];
  __shared__ float nrmp[128], nrmh[128];

  int bx = blockIdx.x;
  int grp = bx >> 6;
  int b = (bx >> 2) & 15;
  int side = (bx >> 1) & 1;
  int rh = bx & 1;
  int fw = !(grp & 1);
  int word = grp < 2;
  int pc = pv_chain(grp);
  const float* PV = G.houtA + (long)pc * HOUT_CH + (long)b * Sz * Hz;
  const float* HV = G.houtA + (long)(pc + 2) * HOUT_CH + (long)b * Sz * Hz;
  int tid = threadIdx.x;
  int w = tid >> 6, lane = tid & 63;

  for (int i = tid; i < 128 * Hz; i += 512) {
    int r = i / Hz, c = i % Hz;
    pvs[r * PVS2 + c] = PV[r * Hz + c];
    hvs[r * PVS2 + c] = HV[r * Hz + c];
  }
  {
    const float* wm = fw ? G.w3 : G.w4;
    const float* wx = fw ? G.w5 : G.w6;
    const float* wf = G.w_full[grp];
    for (int i = tid; i < 60 * Hz; i += 512) {
      int row = i / Hz, c = i % Hz;
      const float* src = (row < 20) ? wf : (row < 40 ? wm : wx);
      int rr = (row < 20) ? row : (row < 40 ? row - 20 : row - 40);
      wl[row * PVS2 + c] = src[rr * Hz + c];
    }
  }
  __syncthreads();
  if (tid < 256) {
    const float* base = (tid < 128) ? pvs : hvs;
    int r = tid & 127;
    float s = 0.f;
    for (int j = 0; j < Hz; ++j) { float v = base[r * PVS2 + j]; s += v * v; }
    if (tid < 128) nrmp[r] = sqrtf(s); else nrmh[r] = sqrtf(s);
  }
  __syncthreads();

  const float* A  = side ? hvs : pvs;
  const float* B  = side ? pvs : hvs;
  const float* nA = side ? nrmh : nrmp;
  const float* nB = side ? nrmp : nrmh;
  int bcrow = fw ? (Sz - 1) : 0;
  float* mvout = G.mv + (long)((word ? 0 : 2) + side) * MV_CH + (long)b * Sz * 120;
  int off = fw ? 0 : 60;
  int type = lane / 20;
  const float* wrow = wl + lane * PVS2;
  float* myatt = attw + w * 128;
  float* myfm = fmean + w * FS;
  float* myfx = fmax + w * FS;

  for (int task = w; task < 64; task += 8) {
    int r = rh * 64 + task;
    const float* ar = A + r * PVS2;
    float d0 = 0.f, d1 = 0.f;
    const float* b0 = B + lane * PVS2;
    const float* b1 = B + (lane + 64) * PVS2;
    for (int j = 0; j < Hz; j += 2) {
      float2 a2 = *(const float2*)(ar + j);
      float2 p2 = *(const float2*)(b0 + j);
      float2 q2 = *(const float2*)(b1 + j);
      d0 += a2.x * p2.x + a2.y * p2.y;
      d1 += a2.x * q2.x + a2.y * q2.y;
    }
    float at0 = d0 / fmaxf(nA[r] * nB[lane], EPSV);
    float at1 = d1 / fmaxf(nA[r] * nB[lane + 64], EPSV);
    myatt[lane] = at0;
    myatt[lane + 64] = at1;
    float s = at0 + at1;
#pragma unroll
    for (int m = 1; m < 64; m <<= 1) s += __shfl_xor(s, m);
    float inv = 1.f / fmaxf(s, EPSV);
    float m0 = 0.f, m1 = 0.f, x0 = -1e30f, x1 = -1e30f;
    const float* bj0 = B + lane;
    const float* bj1 = B + lane + 64;
    for (int q = 0; q < 128; ++q) {
      float aq = myatt[q];
      float v0 = bj0[q * PVS2];
      float v1 = bj1[q * PVS2];
      m0 += aq * v0; x0 = fmaxf(x0, aq * v0);
      m1 += aq * v1; x1 = fmaxf(x1, aq * v1);
    }
    myfm[lane] = m0 * inv;
    myfx[lane] = x0;
    if (lane < Hz - 64) { myfm[lane + 64] = m1 * inv; myfx[lane + 64] = x1; }
    if (lane < 60) {
      const float* v2p = (type == 0) ? (B + bcrow * PVS2)
                       : (type == 1) ? myfm : myfx;
      float num = 0.f, n1 = 0.f, n2 = 0.f;
      for (int j = 0; j < Hz; j += 2) {
        float2 w2 = *(const float2*)(wrow + j);
        float2 a2 = *(const float2*)(ar + j);
        float2 c2 = *(const float2*)(v2p + j);
        float ws0 = w2.x * w2.x, ws1 = w2.y * w2.y;
        num += ws0 * a2.x * c2.x + ws1 * a2.y * c2.y;
        n1  += ws0 * a2.x * a2.x + ws1 * a2.y * a2.y;
        n2  += ws0 * c2.x * c2.x + ws1 * c2.y * c2.y;
      }
      mvout[r * 120 + off + lane] = num / fmaxf(sqrtf(n1) * sqrtf(n2), EPSV);
    }
  }
}

// ---------------- fused head -------------------------------------------------
__global__ __launch_bounds__(1024) void k_head(const float* houtB,
                                               const float* lw, const float* lb,
                                               const float* gw, const float* gb,
                                               const float* f1w, const float* f1b,
                                               const float* f2w, const float* f2b,
                                               float* out) {
  int b = blockIdx.x;
  __shared__ float xr[800];
  __shared__ float hwv[800];
  __shared__ float f1[200];
  int tid = threadIdx.x;
  if (tid < 800) {
    int seq = tid / Gz;
    int i = tid % Gz;
    int seg = i / Hz, j = i % Hz;
    int chain = seq * 4 + seg;
    int s_sel = (seg & 1) ? 0 : (Sz - 1);
    xr[tid] = houtB[((long)chain * Bz + b) * Sz * Hz + (long)s_sel * Hz + j];
  }
  __syncthreads();
  if (tid < 800) {
    int seq = tid / Gz;
    int o = tid % Gz;
    const float* xs = xr + seq * Gz;
    const float* lwr = lw + (long)o * Gz;
    const float* gwr = gw + (long)o * Gz;
    float al = 0.f, ag = 0.f;
#pragma unroll 4
    for (int k = 0; k < Gz; ++k) {
      float x = xs[k];
      al += x * lwr[k];
      ag += x * gwr[k];
    }
    al += lb[o];
    ag += gb[o];
    float hlin = fmaxf(al, 0.f);
    float tg = sigf(ag);
    hwv[tid] = tg * hlin + (1.f - tg) * xs[o];
  }
  __syncthreads();
  if (tid < 200) {
    const float* wr = f1w + (long)tid * 800;
    float acc = f1b[tid];
#pragma unroll 4
    for (int k = 0; k < 800; ++k) acc += hwv[k] * wr[k];
    f1[tid] = tanh_fast(acc);
  }
  __syncthreads();
  if (tid < 3) {
    const float* wr = f2w + tid * 200;
    float acc = f2b[tid];
    for (int k = 0; k < 200; ++k) acc += f1[k] * wr[k];
    out[b * 3 + tid] = acc;
  }
}

// ---------------- host orchestration -----------------------------------------
extern "C" void kernel_launch(void* const* d_in, const int* in_sizes, int n_in,
                              void* d_out, int out_size, void* d_ws, size_t ws_size,
                              hipStream_t stream) {
  (void)in_sizes; (void)n_in; (void)out_size;

  const int* p_ids  = (const int*)d_in[0];
  const int* h_ids  = (const int*)d_in[1];
  const int* cp_ids = (const int*)d_in[2];
  const int* ch_ids = (const int*)d_in[3];
  const float* word_emb = (const float*)d_in[4];
  const float* char_emb = (const float*)d_in[5];
  const float* ctx_Wih_f = (const float*)d_in[6];
  const float* ctx_Whh_f = (const float*)d_in[7];
  const float* ctx_b_f   = (const float*)d_in[8];
  const float* ctx_Wih_b = (const float*)d_in[9];
  const float* ctx_Whh_b = (const float*)d_in[10];
  const float* ctx_b_b   = (const float*)d_in[11];
  const float* chr_Wih_f = (const float*)d_in[12];
  const float* chr_Whh_f = (const float*)d_in[13];
  const float* chr_b_f   = (const float*)d_in[14];
  const float* chr_Wih_b = (const float*)d_in[15];
  const float* chr_Whh_b = (const float*)d_in[16];
  const float* chr_b_b   = (const float*)d_in[17];
  const float* agg_Wih_f = (const float*)d_in[18];
  const float* agg_Whh_f = (const float*)d_in[19];
  const float* agg_b_f   = (const float*)d_in[20];
  const float* agg_Wih_b = (const float*)d_in[21];
  const float* agg_Whh_b = (const float*)d_in[22];
  const float* agg_b_b   = (const float*)d_in[23];
  const float* mp_w1 = (const float*)d_in[24];
  const float* mp_w2 = (const float*)d_in[25];
  const float* mp_w3 = (const float*)d_in[26];
  const float* mp_w4 = (const float*)d_in[27];
  const float* mp_w5 = (const float*)d_in[28];
  const float* mp_w6 = (const float*)d_in[29];
  const float* char_w1 = (const float*)d_in[30];
  const float* char_w2 = (const float*)d_in[31];
  const float* hw_lin_w  = (const float*)d_in[32];
  const float* hw_lin_b  = (const float*)d_in[33];
  const float* hw_gate_w = (const float*)d_in[34];
  const float* hw_gate_b = (const float*)d_in[35];
  const float* fc1_w = (const float*)d_in[36];
  const float* fc1_b = (const float*)d_in[37];
  const float* fc2_w = (const float*)d_in[38];
  const float* fc2_b = (const float*)d_in[39];

  float* ws = (float*)d_ws;
  float* XIN    = ws;                         // 8 * XIN_CH (reused A -> B)
  float* HOUT_A = XIN + 8 * XIN_CH;
  float* HOUT_B = HOUT_A + 8 * HOUT_CH;
  float* MV     = HOUT_B + 8 * HOUT_CH;
  size_t needed = (size_t)((MV + 4 * MV_CH) - ws) * 4;
  if (ws_size < needed) return;

  // ---- 1. fused phase-A projections (block per (chain,t)) ----
  {
    Proj8 pc{};
    const int* idv[8] = {p_ids, p_ids, h_ids, h_ids, cp_ids, cp_ids, ch_ids, ch_ids};
    for (int c = 0; c < 8; ++c) {
      int word = c < 4;
      pc.c[c].ids = idv[c];
      pc.c[c].emb = word ? word_emb : char_emb;
      pc.c[c].src = nullptr;
      pc.c[c].W    = word ? ((c & 1) ? ctx_Wih_b : ctx_Wih_f) : ((c & 1) ? chr_Wih_b : chr_Wih_f);
      pc.c[c].bias = word ? ((c & 1) ? ctx_b_b : ctx_b_f)     : ((c & 1) ? chr_b_b : chr_b_f);
      pc.c[c].out = XIN + c * XIN_CH;
      pc.c[c].rev = c & 1;
      pc.c[c].K = word ? 300 : 50;
      pc.c[c].nch = word ? 10 : 2;
    }
    k_proj<<<8 * Sz, 256, 0, stream>>>(pc);
  }
  // ---- 2. phase-A LSTMs ----
  {
    Lstm8 la{};
    for (int c = 0; c < 8; ++c) {
      la.c[c].xin = XIN + c * XIN_CH;
      la.c[c].Whh = (c < 4) ? ((c & 1) ? ctx_Whh_b : ctx_Whh_f)
                            : ((c & 1) ? chr_Whh_b : chr_Whh_f);
      la.c[c].hout = HOUT_A + c * HOUT_CH;
      la.c[c].rev = c & 1;
      la.c[c].store_all = 1;
    }
    k_lstm<<<8, 512, 0, stream>>>(la);
  }
  // ---- 3. fused branch ----
  {
    BranchArgs g{};
    g.houtA = HOUT_A; g.mv = MV;
    g.w_full[0] = mp_w1; g.w_full[1] = mp_w2; g.w_full[2] = char_w1; g.w_full[3] = char_w2;
    g.w3 = mp_w3; g.w4 = mp_w4; g.w5 = mp_w5; g.w6 = mp_w6;
    k_branch<<<256, 512, 0, stream>>>(g);
  }
  // ---- 4. phase-B projections (K=120) ----
  {
    Proj8 pa{};
    for (int c = 0; c < 8; ++c) {
      pa.c[c].ids = nullptr; pa.c[c].emb = nullptr;
      pa.c[c].src = MV + (c >> 1) * MV_CH;
      pa.c[c].W = (c & 1) ? agg_Wih_b : agg_Wih_f;
      pa.c[c].bias = (c & 1) ? agg_b_b : agg_b_f;
      pa.c[c].out = XIN + c * XIN_CH;
      pa.c[c].rev = c & 1;
      pa.c[c].K = 120;
      pa.c[c].nch = 4;
    }
    k_proj<<<8 * Sz, 256, 0, stream>>>(pa);
  }
  // ---- 5. phase-B LSTMs ----
  {
    Lstm8 la{};
    for (int c = 0; c < 8; ++c) {
      la.c[c].xin = XIN + c * XIN_CH;
      la.c[c].Whh = (c & 1) ? agg_Whh_b : agg_Whh_f;
      la.c[c].hout = HOUT_B + c * HOUT_CH;
      la.c[c].rev = c & 1;
      la.c[c].store_all = 0;
    }
    k_lstm<<<8, 512, 0, stream>>>(la);
  }
  // ---- 6. fused head ----
  k_head<<<Bz, 1024, 0, stream>>>(HOUT_B, hw_lin_w, hw_lin_b, hw_gate_w, hw_gate_b,
                                  fc1_w, fc1_b, fc2_w, fc2_b, (float*)d_out);
}

// Round 11
// 879.264 us; speedup vs baseline: 4.3938x; 1.0787x over previous
//
#include <hip/hip_runtime.h>

// BiMPM on MI355X. Round 11: k_cvt pre-converts the six Wih matrices to
// padded, gate-permuted bf16 rows in ws (once per launch, ~3us). k_proj's
// inner loop shrinks to {1 aligned 16B bf16 load + 2 MFMA} per tile-chunk —
// no per-use fp32->bf16 conversion, no row-permute math, no tail selects.
// All other kernels byte-identical to round 10 (attribution).

#define Bz 16
#define Sz 128
#define Hz 100
#define Gz 400      // 4H
#define NT 25       // Gz/16 n-tiles
#define EPSV 1e-8f

#define XIN_CH  ((long)Sz * Bz * Gz)    // 819200
#define HOUT_CH ((long)Bz * Sz * Hz)    // 204800
#define MV_CH   ((long)Bz * Sz * 120)   // 245760

typedef __attribute__((ext_vector_type(4))) float floatx4;
typedef __attribute__((ext_vector_type(8))) __bf16 bf16x8;

union FragU { bf16x8 v; unsigned u[4]; unsigned short s[8]; };

__device__ __forceinline__ float bf2f(unsigned short h) {
  unsigned u = ((unsigned)h) << 16;
  return __builtin_bit_cast(float, u);
}
__device__ __forceinline__ unsigned short f2bf(float x) {
  unsigned u = __builtin_bit_cast(unsigned, x);
  u = u + 0x7FFFu + ((u >> 16) & 1u);   // RNE
  return (unsigned short)(u >> 16);
}
__device__ __forceinline__ float sigf(float x) { return 1.0f / (1.0f + __expf(-x)); }
__device__ __forceinline__ float tanh_fast(float x) { return 1.0f - 2.0f / (__expf(2.0f * x) + 1.0f); }

// workgroup barrier that does NOT drain vmcnt: LDS-visibility only.
__device__ __forceinline__ void barrier_lds_only() {
  __asm__ __volatile__("s_waitcnt lgkmcnt(0)\ns_barrier" ::: "memory");
}

#define MFMA(a, b, c) __builtin_amdgcn_mfma_f32_16x16x32_bf16((a), (b), (c), 0, 0, 0)

__device__ __forceinline__ int pv_chain(int grp) { return (grp < 2 ? 0 : 4) + (grp & 1); }

// ---------------- weight pre-conversion: fp32 -> bf16, permuted+padded rows ---
// dst row p (p = hidden*4+gate) = src row (p&3)*Hz + (p>>2), padded to KP.
struct CvtDesc { const float* src; unsigned short* dst; int K; int KP; };
struct Cvt6 { CvtDesc d[6]; };

__global__ __launch_bounds__(64) void k_cvt(Cvt6 C) {
  int bx = blockIdx.x;
  int m = bx / Gz;
  int p = bx % Gz;
  CvtDesc d = C.d[m];
  int orig = (p & 3) * Hz + (p >> 2);
  const float* src = d.src + (long)orig * d.K;
  unsigned short* dst = d.dst + (long)p * d.KP;
  for (int k = threadIdx.x; k < d.KP; k += 64)
    dst[k] = (k < d.K) ? f2bf(src[k]) : 0;
}

// ---------------- projection GEMM: block per (chain,t), LDS-staged tokens -----
// out[t][b][p]; W16 = pre-converted bf16, permuted rows, stride KP.
struct ProjChain {
  const int* ids;
  const float* emb;
  const float* src;
  const unsigned short* W16;  // G x KP bf16 (permuted rows, zero-padded)
  const float* bias;          // G fp32 (original order)
  float* out;                 // [t][b][p] fp32, gate-interleaved p
  int rev;
  int K;
  int nch;                    // KP/32
};
struct Proj8 { ProjChain c[8]; };

#define PPS 328   // staged token row stride in ushort

__global__ __launch_bounds__(256) void k_proj(Proj8 P) {
  __shared__ __align__(16) unsigned short phi[16 * PPS];
  __shared__ __align__(16) unsigned short plo[16 * PPS];

  int bx = blockIdx.x;
  int c = bx >> 7;
  int t = bx & 127;
  const ProjChain ch = P.c[c];
  const int K = ch.K;
  const int KP = ch.nch * 32;
  int tp = ch.rev ? (Sz - 1 - t) : t;
  int tid = threadIdx.x;

  // stage tokens once: fp32 -> packed bf16 hi/lo
  for (int i = tid; i < 16 * KP; i += 256) {
    int b = i / KP, k = i % KP;
    float v = 0.f;
    if (k < K) {
      const float* row = ch.ids ? (ch.emb + (long)ch.ids[b * Sz + tp] * K)
                                : (ch.src + ((long)b * Sz + tp) * K);
      v = row[k];
    }
    unsigned short hh = f2bf(v);
    phi[b * PPS + k] = hh;
    plo[b * PPS + k] = f2bf(v - bf2f(hh));
  }
  __syncthreads();

  int w = tid >> 6, lane = tid & 63;
  int nl = lane & 15, qd = lane >> 4;
  floatx4 acc[7];
#pragma unroll
  for (int i = 0; i < 7; ++i) acc[i] = floatx4{0.f, 0.f, 0.f, 0.f};

  // per-tile W row bases (hoisted)
  const unsigned short* wbase[7];
#pragma unroll
  for (int i = 0; i < 7; ++i) {
    int nt = w + 4 * i;
    wbase[i] = (nt < NT) ? (ch.W16 + (long)(nt * 16 + nl) * KP) : ch.W16;
  }

  for (int cc = 0; cc < ch.nch; ++cc) {
    FragU bhi, blo;
    bhi.v = *(const bf16x8*)&phi[nl * PPS + cc * 32 + qd * 8];
    blo.v = *(const bf16x8*)&plo[nl * PPS + cc * 32 + qd * 8];
    int ko = cc * 32 + qd * 8;
#pragma unroll
    for (int i = 0; i < 7; ++i) {
      if (w + 4 * i < NT) {
        FragU whi;
        whi.v = *(const bf16x8*)(wbase[i] + ko);
        acc[i] = MFMA(whi.v, bhi.v, acc[i]);
        acc[i] = MFMA(whi.v, blo.v, acc[i]);
      }
    }
  }
#pragma unroll
  for (int i = 0; i < 7; ++i) {
    int nt = w + 4 * i;
    if (nt < NT) {
#pragma unroll
      for (int r = 0; r < 4; ++r) {
        int p = nt * 16 + qd * 4 + r;
        acc[i][r] += ch.bias[(p & 3) * Hz + (p >> 2)];
      }
      *(floatx4*)(ch.out + ((long)t * Bz + nl) * Gz + nt * 16 + qd * 4) = acc[i];
    }
  }
}

// ---------------- LSTM scan: one workgroup (8 waves) per chain ----------------
struct LstmChain {
  const float* xin;     // [t][b][p] gate-interleaved
  const float* Whh;     // G x H fp32 (original row order)
  float* hout;          // B x S x H fp32
  int rev;
  int store_all;
};
struct Lstm8 { LstmChain c[8]; };

#define NW 8      // waves per block
#define TPW 4     // max tiles per wave; tile = i*NW + w
#define NCH 7     // K' chunks of 32 (K'=224, valid 200)
#define HPR 232   // packed h row stride in bf16

__global__ __launch_bounds__(512, 2) void k_lstm(Lstm8 P) {
  __shared__ __align__(16) unsigned short hpk[2][Bz * HPR];  // packed {hi,lo}
  __shared__ float hfp[2][Bz * Hz];                          // fp32 h stage

  const LstmChain ch = P.c[blockIdx.x];
  const int tid = threadIdx.x;
  const int w = tid >> 6;
  const int lane = tid & 63;
  const int nl = lane & 15;
  const int qd = lane >> 4;

  for (int i = tid; i < 2 * Bz * HPR / 2; i += 512) ((unsigned*)hpk)[i] = 0;
  __syncthreads();

  FragU wa[TPW][NCH];
#pragma unroll
  for (int i = 0; i < TPW; ++i) {
    int tile = i * NW + w;
    if (tile < NT) {
      int pA = tile * 16 + nl;
      const float* wr = ch.Whh + (long)((pA & 3) * Hz + (pA >> 2)) * Hz;
#pragma unroll
      for (int cc = 0; cc < NCH; ++cc) {
#pragma unroll
        for (int j = 0; j < 8; ++j) {
          int k = cc * 16 + qd * 4 + (j >> 1);
          wa[i][cc].s[j] = f2bf((k < Hz) ? wr[k] : 0.f);
        }
      }
    }
  }

  floatx4 xc[TPW], xn[TPW];
  float cstate[TPW];
#pragma unroll
  for (int i = 0; i < TPW; ++i) {
    cstate[i] = 0.f;
    xc[i] = floatx4{0.f, 0.f, 0.f, 0.f};
    if (i * NW + w < NT)
      xc[i] = *(const floatx4*)(ch.xin + (long)nl * Gz + (i * NW + w) * 16 + qd * 4);
  }

  for (int t = 0; t < Sz; ++t) {
    if (ch.store_all && t > 0) {
      int pb = (t - 1) & 1;
      int sprev = ch.rev ? (Sz - t) : (t - 1);
#pragma unroll
      for (int it = 0; it < 4; ++it) {
        int idx = tid + it * 512;
        if (idx < Bz * Hz)
          ch.hout[((long)(idx / Hz) * Sz + sprev) * Hz + (idx % Hz)] = hfp[pb][idx];
      }
    }
    if (t + 1 < Sz) {
      const float* xp = ch.xin + (long)(t + 1) * Bz * Gz + (long)nl * Gz;
#pragma unroll
      for (int i = 0; i < TPW; ++i)
        if (i * NW + w < NT)
          xn[i] = *(const floatx4*)(xp + (i * NW + w) * 16 + qd * 4);
    }
    const int rp = t & 1;
    floatx4 acc[TPW];
#pragma unroll
    for (int i = 0; i < TPW; ++i) acc[i] = xc[i];
#pragma unroll
    for (int cc = 0; cc < NCH; ++cc) {
      FragU bh;
      bh.v = *(const bf16x8*)(&hpk[rp][nl * HPR + cc * 32 + qd * 8]);
#pragma unroll
      for (int i = 0; i < TPW; ++i)
        if (i * NW + w < NT) acc[i] = MFMA(wa[i][cc].v, bh.v, acc[i]);
    }
    const int wp = rp ^ 1;
    const bool keep = ch.store_all || (t == Sz - 1);
#pragma unroll
    for (int i = 0; i < TPW; ++i) {
      int tile = i * NW + w;
      if (tile < NT) {
        float cn = sigf(acc[i][1]) * cstate[i] + sigf(acc[i][0]) * tanh_fast(acc[i][2]);
        float h = sigf(acc[i][3]) * tanh_fast(cn);
        cstate[i] = cn;
        int hd = tile * 4 + qd;
        unsigned short hh = f2bf(h);
        unsigned short hl = f2bf(h - bf2f(hh));
        *(unsigned*)(&hpk[wp][nl * HPR + 2 * hd]) = (unsigned)hh | ((unsigned)hl << 16);
        if (keep) hfp[t & 1][nl * Hz + hd] = h;
      }
    }
    barrier_lds_only();
#pragma unroll
    for (int i = 0; i < TPW; ++i) xc[i] = xn[i];
  }
  {
    int pb = (Sz - 1) & 1;
    int slast = ch.rev ? 0 : (Sz - 1);
#pragma unroll
    for (int it = 0; it < 4; ++it) {
      int idx = tid + it * 512;
      if (idx < Bz * Hz)
        ch.hout[((long)(idx / Hz) * Sz + slast) * Hz + (idx % Hz)] = hfp[pb][idx];
    }
  }
}

// ---------------- fused branch: att + feats + match, one kernel ---------------
#define PVS2 102   // padded row stride (floats)
#define FS 104     // feat scratch stride

struct BranchArgs {
  const float* houtA;
  float* mv;
  const float* w_full[4];
  const float* w3; const float* w4; const float* w5; const float* w6;
};

__global__ __launch_bounds__(512, 1) void k_branch(BranchArgs G) {
  __shared__ float pvs[128 * PVS2];
  __shared__ float hvs[128 * PVS2 + 32];   // +pad: feats j+64 lane overread
  __shared__ float wl[60 * PVS2];
  __shared__ float attw[8 * 128];
  __shared__ float fmean[8 * FS];
  __shared__ float fmax[8 * FS];
  __shared__ float nrmp[128], nrmh[128];

  int bx = blockIdx.x;
  int grp = bx >> 6;
  int b = (bx >> 2) & 15;
  int side = (bx >> 1) & 1;
  int rh = bx & 1;
  int fw = !(grp & 1);
  int word = grp < 2;
  int pc = pv_chain(grp);
  const float* PV = G.houtA + (long)pc * HOUT_CH + (long)b * Sz * Hz;
  const float* HV = G.houtA + (long)(pc + 2) * HOUT_CH + (long)b * Sz * Hz;
  int tid = threadIdx.x;
  int w = tid >> 6, lane = tid & 63;

  for (int i = tid; i < 128 * Hz; i += 512) {
    int r = i / Hz, c = i % Hz;
    pvs[r * PVS2 + c] = PV[r * Hz + c];
    hvs[r * PVS2 + c] = HV[r * Hz + c];
  }
  {
    const float* wm = fw ? G.w3 : G.w4;
    const float* wx = fw ? G.w5 : G.w6;
    const float* wf = G.w_full[grp];
    for (int i = tid; i < 60 * Hz; i += 512) {
      int row = i / Hz, c = i % Hz;
      const float* src = (row < 20) ? wf : (row < 40 ? wm : wx);
      int rr = (row < 20) ? row : (row < 40 ? row - 20 : row - 40);
      wl[row * PVS2 + c] = src[rr * Hz + c];
    }
  }
  __syncthreads();
  if (tid < 256) {
    const float* base = (tid < 128) ? pvs : hvs;
    int r = tid & 127;
    float s = 0.f;
    for (int j = 0; j < Hz; ++j) { float v = base[r * PVS2 + j]; s += v * v; }
    if (tid < 128) nrmp[r] = sqrtf(s); else nrmh[r] = sqrtf(s);
  }
  __syncthreads();

  const float* A  = side ? hvs : pvs;
  const float* B  = side ? pvs : hvs;
  const float* nA = side ? nrmh : nrmp;
  const float* nB = side ? nrmp : nrmh;
  int bcrow = fw ? (Sz - 1) : 0;
  float* mvout = G.mv + (long)((word ? 0 : 2) + side) * MV_CH + (long)b * Sz * 120;
  int off = fw ? 0 : 60;
  int type = lane / 20;
  const float* wrow = wl + lane * PVS2;
  float* myatt = attw + w * 128;
  float* myfm = fmean + w * FS;
  float* myfx = fmax + w * FS;

  for (int task = w; task < 64; task += 8) {
    int r = rh * 64 + task;
    const float* ar = A + r * PVS2;
    float d0 = 0.f, d1 = 0.f;
    const float* b0 = B + lane * PVS2;
    const float* b1 = B + (lane + 64) * PVS2;
    for (int j = 0; j < Hz; j += 2) {
      float2 a2 = *(const float2*)(ar + j);
      float2 p2 = *(const float2*)(b0 + j);
      float2 q2 = *(const float2*)(b1 + j);
      d0 += a2.x * p2.x + a2.y * p2.y;
      d1 += a2.x * q2.x + a2.y * q2.y;
    }
    float at0 = d0 / fmaxf(nA[r] * nB[lane], EPSV);
    float at1 = d1 / fmaxf(nA[r] * nB[lane + 64], EPSV);
    myatt[lane] = at0;
    myatt[lane + 64] = at1;
    float s = at0 + at1;
#pragma unroll
    for (int m = 1; m < 64; m <<= 1) s += __shfl_xor(s, m);
    float inv = 1.f / fmaxf(s, EPSV);
    float m0 = 0.f, m1 = 0.f, x0 = -1e30f, x1 = -1e30f;
    const float* bj0 = B + lane;
    const float* bj1 = B + lane + 64;
    for (int q = 0; q < 128; ++q) {
      float aq = myatt[q];
      float v0 = bj0[q * PVS2];
      float v1 = bj1[q * PVS2];
      m0 += aq * v0; x0 = fmaxf(x0, aq * v0);
      m1 += aq * v1; x1 = fmaxf(x1, aq * v1);
    }
    myfm[lane] = m0 * inv;
    myfx[lane] = x0;
    if (lane < Hz - 64) { myfm[lane + 64] = m1 * inv; myfx[lane + 64] = x1; }
    if (lane < 60) {
      const float* v2p = (type == 0) ? (B + bcrow * PVS2)
                       : (type == 1) ? myfm : myfx;
      float num = 0.f, n1 = 0.f, n2 = 0.f;
      for (int j = 0; j < Hz; j += 2) {
        float2 w2 = *(const float2*)(wrow + j);
        float2 a2 = *(const float2*)(ar + j);
        float2 c2 = *(const float2*)(v2p + j);
        float ws0 = w2.x * w2.x, ws1 = w2.y * w2.y;
        num += ws0 * a2.x * c2.x + ws1 * a2.y * c2.y;
        n1  += ws0 * a2.x * a2.x + ws1 * a2.y * a2.y;
        n2  += ws0 * c2.x * c2.x + ws1 * c2.y * c2.y;
      }
      mvout[r * 120 + off + lane] = num / fmaxf(sqrtf(n1) * sqrtf(n2), EPSV);
    }
  }
}

// ---------------- fused head -------------------------------------------------
__global__ __launch_bounds__(1024) void k_head(const float* houtB,
                                               const float* lw, const float* lb,
                                               const float* gw, const float* gb,
                                               const float* f1w, const float* f1b,
                                               const float* f2w, const float* f2b,
                                               float* out) {
  int b = blockIdx.x;
  __shared__ float xr[800];
  __shared__ float hwv[800];
  __shared__ float f1[200];
  int tid = threadIdx.x;
  if (tid < 800) {
    int seq = tid / Gz;
    int i = tid % Gz;
    int seg = i / Hz, j = i % Hz;
    int chain = seq * 4 + seg;
    int s_sel = (seg & 1) ? 0 : (Sz - 1);
    xr[tid] = houtB[((long)chain * Bz + b) * Sz * Hz + (long)s_sel * Hz + j];
  }
  __syncthreads();
  if (tid < 800) {
    int seq = tid / Gz;
    int o = tid % Gz;
    const float* xs = xr + seq * Gz;
    const float* lwr = lw + (long)o * Gz;
    const float* gwr = gw + (long)o * Gz;
    float al = 0.f, ag = 0.f;
#pragma unroll 4
    for (int k = 0; k < Gz; ++k) {
      float x = xs[k];
      al += x * lwr[k];
      ag += x * gwr[k];
    }
    al += lb[o];
    ag += gb[o];
    float hlin = fmaxf(al, 0.f);
    float tg = sigf(ag);
    hwv[tid] = tg * hlin + (1.f - tg) * xs[o];
  }
  __syncthreads();
  if (tid < 200) {
    const float* wr = f1w + (long)tid * 800;
    float acc = f1b[tid];
#pragma unroll 4
    for (int k = 0; k < 800; ++k) acc += hwv[k] * wr[k];
    f1[tid] = tanh_fast(acc);
  }
  __syncthreads();
  if (tid < 3) {
    const float* wr = f2w + tid * 200;
    float acc = f2b[tid];
    for (int k = 0; k < 200; ++k) acc += f1[k] * wr[k];
    out[b * 3 + tid] = acc;
  }
}

// ---------------- host orchestration -----------------------------------------
extern "C" void kernel_launch(void* const* d_in, const int* in_sizes, int n_in,
                              void* d_out, int out_size, void* d_ws, size_t ws_size,
                              hipStream_t stream) {
  (void)in_sizes; (void)n_in; (void)out_size;

  const int* p_ids  = (const int*)d_in[0];
  const int* h_ids  = (const int*)d_in[1];
  const int* cp_ids = (const int*)d_in[2];
  const int* ch_ids = (const int*)d_in[3];
  const float* word_emb = (const float*)d_in[4];
  const float* char_emb = (const float*)d_in[5];
  const float* ctx_Wih_f = (const float*)d_in[6];
  const float* ctx_Whh_f = (const float*)d_in[7];
  const float* ctx_b_f   = (const float*)d_in[8];
  const float* ctx_Wih_b = (const float*)d_in[9];
  const float* ctx_Whh_b = (const float*)d_in[10];
  const float* ctx_b_b   = (const float*)d_in[11];
  const float* chr_Wih_f = (const float*)d_in[12];
  const float* chr_Whh_f = (const float*)d_in[13];
  const float* chr_b_f   = (const float*)d_in[14];
  const float* chr_Wih_b = (const float*)d_in[15];
  const float* chr_Whh_b = (const float*)d_in[16];
  const float* chr_b_b   = (const float*)d_in[17];
  const float* agg_Wih_f = (const float*)d_in[18];
  const float* agg_Whh_f = (const float*)d_in[19];
  const float* agg_b_f   = (const float*)d_in[20];
  const float* agg_Wih_b = (const float*)d_in[21];
  const float* agg_Whh_b = (const float*)d_in[22];
  const float* agg_b_b   = (const float*)d_in[23];
  const float* mp_w1 = (const float*)d_in[24];
  const float* mp_w2 = (const float*)d_in[25];
  const float* mp_w3 = (const float*)d_in[26];
  const float* mp_w4 = (const float*)d_in[27];
  const float* mp_w5 = (const float*)d_in[28];
  const float* mp_w6 = (const float*)d_in[29];
  const float* char_w1 = (const float*)d_in[30];
  const float* char_w2 = (const float*)d_in[31];
  const float* hw_lin_w  = (const float*)d_in[32];
  const float* hw_lin_b  = (const float*)d_in[33];
  const float* hw_gate_w = (const float*)d_in[34];
  const float* hw_gate_b = (const float*)d_in[35];
  const float* fc1_w = (const float*)d_in[36];
  const float* fc1_b = (const float*)d_in[37];
  const float* fc2_w = (const float*)d_in[38];
  const float* fc2_b = (const float*)d_in[39];

  float* ws = (float*)d_ws;
  float* XIN    = ws;                         // 8 * XIN_CH (reused A -> B)
  float* HOUT_A = XIN + 8 * XIN_CH;
  float* HOUT_B = HOUT_A + 8 * HOUT_CH;
  float* MV     = HOUT_B + 8 * HOUT_CH;
  unsigned short* WC = (unsigned short*)(MV + 4 * MV_CH);
  // bf16 W buffers: ctx f/b (KP=320), chr f/b (KP=64), agg f/b (KP=128)
  unsigned short* W_ctx_f = WC;
  unsigned short* W_ctx_b = W_ctx_f + (long)Gz * 320;
  unsigned short* W_chr_f = W_ctx_b + (long)Gz * 320;
  unsigned short* W_chr_b = W_chr_f + (long)Gz * 64;
  unsigned short* W_agg_f = W_chr_b + (long)Gz * 64;
  unsigned short* W_agg_b = W_agg_f + (long)Gz * 128;
  size_t needed = (size_t)((char*)(W_agg_b + (long)Gz * 128) - (char*)ws);
  if (ws_size < needed) return;

  // ---- 0. weight pre-conversion ----
  {
    Cvt6 cv{};
    cv.d[0] = {ctx_Wih_f, W_ctx_f, 300, 320};
    cv.d[1] = {ctx_Wih_b, W_ctx_b, 300, 320};
    cv.d[2] = {chr_Wih_f, W_chr_f, 50, 64};
    cv.d[3] = {chr_Wih_b, W_chr_b, 50, 64};
    cv.d[4] = {agg_Wih_f, W_agg_f, 120, 128};
    cv.d[5] = {agg_Wih_b, W_agg_b, 120, 128};
    k_cvt<<<6 * Gz, 64, 0, stream>>>(cv);
  }
  // ---- 1. fused phase-A projections (block per (chain,t)) ----
  {
    Proj8 pc{};
    const int* idv[8] = {p_ids, p_ids, h_ids, h_ids, cp_ids, cp_ids, ch_ids, ch_ids};
    for (int c = 0; c < 8; ++c) {
      int word = c < 4;
      pc.c[c].ids = idv[c];
      pc.c[c].emb = word ? word_emb : char_emb;
      pc.c[c].src = nullptr;
      pc.c[c].W16  = word ? ((c & 1) ? W_ctx_b : W_ctx_f) : ((c & 1) ? W_chr_b : W_chr_f);
      pc.c[c].bias = word ? ((c & 1) ? ctx_b_b : ctx_b_f) : ((c & 1) ? chr_b_b : chr_b_f);
      pc.c[c].out = XIN + c * XIN_CH;
      pc.c[c].rev = c & 1;
      pc.c[c].K = word ? 300 : 50;
      pc.c[c].nch = word ? 10 : 2;
    }
    k_proj<<<8 * Sz, 256, 0, stream>>>(pc);
  }
  // ---- 2. phase-A LSTMs ----
  {
    Lstm8 la{};
    for (int c = 0; c < 8; ++c) {
      la.c[c].xin = XIN + c * XIN_CH;
      la.c[c].Whh = (c < 4) ? ((c & 1) ? ctx_Whh_b : ctx_Whh_f)
                            : ((c & 1) ? chr_Whh_b : chr_Whh_f);
      la.c[c].hout = HOUT_A + c * HOUT_CH;
      la.c[c].rev = c & 1;
      la.c[c].store_all = 1;
    }
    k_lstm<<<8, 512, 0, stream>>>(la);
  }
  // ---- 3. fused branch ----
  {
    BranchArgs g{};
    g.houtA = HOUT_A; g.mv = MV;
    g.w_full[0] = mp_w1; g.w_full[1] = mp_w2; g.w_full[2] = char_w1; g.w_full[3] = char_w2;
    g.w3 = mp_w3; g.w4 = mp_w4; g.w5 = mp_w5; g.w6 = mp_w6;
    k_branch<<<256, 512, 0, stream>>>(g);
  }
  // ---- 4. phase-B projections (K=120) ----
  {
    Proj8 pa{};
    for (int c = 0; c < 8; ++c) {
      pa.c[c].ids = nullptr; pa.c[c].emb = nullptr;
      pa.c[c].src = MV + (c >> 1) * MV_CH;
      pa.c[c].W16 = (c & 1) ? W_agg_b : W_agg_f;
      pa.c[c].bias = (c & 1) ? agg_b_b : agg_b_f;
      pa.c[c].out = XIN + c * XIN_CH;
      pa.c[c].rev = c & 1;
      pa.c[c].K = 120;
      pa.c[c].nch = 4;
    }
    k_proj<<<8 * Sz, 256, 0, stream>>>(pa);
  }
  // ---- 5. phase-B LSTMs ----
  {
    Lstm8 la{};
    for (int c = 0; c < 8; ++c) {
      la.c[c].xin = XIN + c * XIN_CH;
      la.c[c].Whh = (c & 1) ? agg_Whh_b : agg_Whh_f;
      la.c[c].hout = HOUT_B + c * HOUT_CH;
      la.c[c].rev = c & 1;
      la.c[c].store_all = 0;
    }
    k_lstm<<<8, 512, 0, stream>>>(la);
  }
  // ---- 6. fused head ----
  k_head<<<Bz, 1024, 0, stream>>>(HOUT_B, hw_lin_w, hw_lin_b, hw_gate_w, hw_gate_b,
                                  fc1_w, fc1_b, fc2_w, fc2_b, (float*)d_out);
}